// Round 11
// baseline (216.000 us; speedup 1.0000x reference)
//
#include <hip/hip_runtime.h>
#include <hip/hip_bf16.h>
#include <math.h>

#define NPTS 4096
#define FIN 512
#define FOUT 64

typedef __attribute__((ext_vector_type(8))) short bf16x8;
typedef __attribute__((ext_vector_type(4))) float f32x4;

static __device__ __forceinline__ unsigned short bfbits(float x) {
  __hip_bfloat16 b = __float2bfloat16(x);
  return *reinterpret_cast<unsigned short*>(&b);
}

static __device__ __forceinline__ float wsum64(float v) {
  #pragma unroll
  for (int mm = 1; mm < 64; mm <<= 1) v += __shfl_xor(v, mm);
  return v;
}

static __device__ __forceinline__ int aloadi(int* p) {
  return __hip_atomic_load(p, __ATOMIC_RELAXED, __HIP_MEMORY_SCOPE_AGENT);
}
static __device__ __forceinline__ float aloadf(float* p) {
  return __hip_atomic_load(p, __ATOMIC_RELAXED, __HIP_MEMORY_SCOPE_AGENT);
}
static __device__ __forceinline__ void axchf(float* p, float v) {
  float old = atomicExch(p, v);
  asm volatile("" :: "v"(old));
}

// ---------------- prep: bf16 h, row norms, m1 init; WbT; zero barriers ----------------
__global__ __launch_bounds__(256) void k_prep(const float* __restrict__ h,
    const float* __restrict__ W, __hip_bfloat16* __restrict__ xb,
    float* __restrict__ sq, int* __restrict__ m1, __hip_bfloat16* __restrict__ WbT,
    int* __restrict__ barZ) {
  int bid = blockIdx.x, t = threadIdx.x;
  if (bid >= 1026) {                 // zero barrier counters
    if (t < 32) barZ[t] = 0;
    return;
  }
  if (bid >= 1024) {                 // W -> WbT[n][k]
    int base = (bid - 1024) * 16384;
    for (int rep = 0; rep < 64; ++rep) {
      int e = base + rep * 256 + t;
      int n = e >> 9, k = e & 511;
      WbT[e] = __float2bfloat16(W[k * FOUT + n]);
    }
    return;
  }
  int lane = t & 63, wid = t >> 6;
  int row = bid * 4 + wid;
  const float4* hr = (const float4*)(h + (size_t)row * FIN);
  float4 a = hr[lane], b = hr[64 + lane];
  ushort4 pa = { bfbits(a.x), bfbits(a.y), bfbits(a.z), bfbits(a.w) };
  ushort4 pb = { bfbits(b.x), bfbits(b.y), bfbits(b.z), bfbits(b.w) };
  *(ushort4*)(xb + (size_t)row * FIN + 4 * lane) = pa;
  *(ushort4*)(xb + (size_t)row * FIN + 256 + 4 * lane) = pb;
  float s = a.x*a.x + a.y*a.y + a.z*a.z + a.w*a.w
          + b.x*b.x + b.y*b.y + b.z*b.z + b.w*b.w;
  s = wsum64(s);
  if (lane == 0) { sq[row] = s; m1[row] = 0x7F800000; }
}

// ---------------- gram full-tile role: 128x128, 256 active threads ----------------
__device__ __forceinline__ void gram_role(const __hip_bfloat16* __restrict__ xb,
    const float* __restrict__ sq, int* __restrict__ m1, int gb, char* smem) {
  bool act = threadIdx.x < 256;
  int tid = threadIdx.x;
  int lane = tid & 63, wid = tid >> 6;
  int b = gb, I = 0;
  while (b >= 32 - I) { b -= 32 - I; ++I; }
  int J = I + b;
  char* As = smem;
  char* Bs = smem + 16384;

  int R0 = I * 128, C0 = J * 128;
  int rowBase = (wid >> 1) * 64;
  int colBase = (wid & 1) * 64;
  int lrow = lane & 15, hi = lane >> 4, rsub = hi * 4;

  f32x4 acc[4][4];
  #pragma unroll
  for (int p = 0; p < 4; ++p)
    #pragma unroll
    for (int q = 0; q < 4; ++q)
      acc[p][q] = (f32x4){0.f, 0.f, 0.f, 0.f};

  int srow = lane >> 3;
  int scol = ((lane & 7) ^ srow) * 8;
  const __hip_bfloat16* gA = xb + (size_t)(R0 + (wid & 3) * 32 + srow) * FIN + scol;
  const __hip_bfloat16* gB = xb + (size_t)(C0 + (wid & 3) * 32 + srow) * FIN + scol;
  char* lA = As + (wid & 3) * 4096;
  char* lB = Bs + (wid & 3) * 4096;
  int rdswz = (lrow & 7) << 4;

  for (int kt = 0; kt < 8; ++kt) {
    int K0 = kt * 64;
    if (act) {
      #pragma unroll
      for (int j = 0; j < 4; ++j) {
        __builtin_amdgcn_global_load_lds(
            (const __attribute__((address_space(1))) unsigned int*)(gA + (size_t)(8 * j) * FIN + K0),
            (__attribute__((address_space(3))) unsigned int*)(lA + j * 1024), 16, 0, 0);
        __builtin_amdgcn_global_load_lds(
            (const __attribute__((address_space(1))) unsigned int*)(gB + (size_t)(8 * j) * FIN + K0),
            (__attribute__((address_space(3))) unsigned int*)(lB + j * 1024), 16, 0, 0);
      }
    }
    __syncthreads();
    if (act) {
      #pragma unroll
      for (int s = 0; s < 2; ++s) {
        int k0b = s * 64;
        bf16x8 av[4], bw[4];
        #pragma unroll
        for (int f = 0; f < 4; ++f) {
          int arow = rowBase + f * 16 + lrow;
          av[f] = *(const bf16x8*)(As + arow * 128 + ((k0b + hi * 16) ^ rdswz));
          int brow = colBase + f * 16 + lrow;
          bw[f] = *(const bf16x8*)(Bs + brow * 128 + ((k0b + hi * 16) ^ rdswz));
        }
        #pragma unroll
        for (int fi = 0; fi < 4; ++fi)
          #pragma unroll
          for (int fj = 0; fj < 4; ++fj)
            acc[fi][fj] = __builtin_amdgcn_mfma_f32_16x16x32_bf16(av[fi], bw[fj], acc[fi][fj], 0, 0, 0);
      }
    }
    __syncthreads();
  }
  if (!act) return;

  int rowBaseG = R0 + rowBase, colBaseG = C0 + colBase;
  float sqr[16], sqc4[4];
  #pragma unroll
  for (int fi = 0; fi < 4; ++fi)
    #pragma unroll
    for (int rg = 0; rg < 4; ++rg)
      sqr[fi * 4 + rg] = sq[rowBaseG + fi * 16 + rsub + rg];
  #pragma unroll
  for (int fj = 0; fj < 4; ++fj) sqc4[fj] = sq[colBaseG + fj * 16 + lrow];

  float rmin[16], cmin[4];
  #pragma unroll
  for (int q = 0; q < 16; ++q) rmin[q] = INFINITY;
  #pragma unroll
  for (int q = 0; q < 4; ++q) cmin[q] = INFINITY;

  #pragma unroll
  for (int fi = 0; fi < 4; ++fi)
    #pragma unroll
    for (int fj = 0; fj < 4; ++fj)
      #pragma unroll
      for (int rg = 0; rg < 4; ++rg) {
        int r = rowBaseG + fi * 16 + rsub + rg;
        int c = colBaseG + fj * 16 + lrow;
        float d2 = sqr[fi * 4 + rg] + sqc4[fj] - 2.f * acc[fi][fj][rg];
        if (r == c) d2 = INFINITY;
        rmin[fi * 4 + rg] = fminf(rmin[fi * 4 + rg], d2);
        cmin[fj] = fminf(cmin[fj], d2);
      }

  #pragma unroll
  for (int mm = 1; mm < 16; mm <<= 1) {
    #pragma unroll
    for (int q = 0; q < 16; ++q) rmin[q] = fminf(rmin[q], __shfl_xor(rmin[q], mm));
  }
  if ((lane & 15) == 0) {
    #pragma unroll
    for (int q = 0; q < 16; ++q) {
      int r = rowBaseG + (q >> 2) * 16 + rsub + (q & 3);
      atomicMin(&m1[r], __float_as_int(rmin[q]));
    }
  }
  if (I != J) {
    #pragma unroll
    for (int mm = 16; mm < 64; mm <<= 1) {
      #pragma unroll
      for (int q = 0; q < 4; ++q) cmin[q] = fminf(cmin[q], __shfl_xor(cmin[q], mm));
    }
    if ((lane >> 4) == 0) {
      #pragma unroll
      for (int q = 0; q < 4; ++q)
        atomicMin(&m1[colBaseG + q * 16 + lane], __float_as_int(cmin[q]));
    }
  }
}

// ---------------- Wh = xb @ WbT^T via MFMA; also writes WhbT (transposed bf16) ----------------
__device__ __forceinline__ void whmm_role(const __hip_bfloat16* __restrict__ xb,
    const __hip_bfloat16* __restrict__ WbT, float* __restrict__ Wh,
    __hip_bfloat16* __restrict__ WhbT, int wb) {
  int t = threadIdx.x, lane = t & 63, wid = t >> 6;
  int r16 = lane & 15, hi = lane >> 4;
  int rbase = wb * 128 + wid * 16;
  f32x4 acc[4];
  #pragma unroll
  for (int fn = 0; fn < 4; ++fn) acc[fn] = (f32x4){0.f, 0.f, 0.f, 0.f};
  const __hip_bfloat16* aP = xb + (size_t)(rbase + r16) * FIN + hi * 8;
  const __hip_bfloat16* bP[4];
  #pragma unroll
  for (int fn = 0; fn < 4; ++fn)
    bP[fn] = WbT + (size_t)(fn * 16 + r16) * FIN + hi * 8;
  #pragma unroll
  for (int kk = 0; kk < 16; ++kk) {
    bf16x8 a = *(const bf16x8*)(aP + kk * 32);
    #pragma unroll
    for (int fn = 0; fn < 4; ++fn) {
      bf16x8 bw = *(const bf16x8*)(bP[fn] + kk * 32);
      acc[fn] = __builtin_amdgcn_mfma_f32_16x16x32_bf16(a, bw, acc[fn], 0, 0, 0);
    }
  }
  #pragma unroll
  for (int fn = 0; fn < 4; ++fn)
    #pragma unroll
    for (int q = 0; q < 4; ++q) {
      float v = acc[fn][q];
      Wh[(size_t)(rbase + hi * 4 + q) * FOUT + fn * 16 + r16] = v;
      WhbT[(size_t)(fn * 16 + r16) * NPTS + rbase + hi * 4 + q] = __float2bfloat16(v);
    }
}

// ---------------- row loader ----------------
__device__ __forceinline__ void load_rows(const float* __restrict__ h, int rbase,
    int lane, float x[8][8]) {
  #pragma unroll
  for (int r = 0; r < 8; ++r) {
    const float4* xr = (const float4*)(h + (size_t)(rbase + r) * FIN);
    float4 u0 = xr[2 * lane], u1 = xr[2 * lane + 1];
    x[r][0]=u0.x; x[r][1]=u0.y; x[r][2]=u0.z; x[r][3]=u0.w;
    x[r][4]=u1.x; x[r][5]=u1.y; x[r][6]=u1.z; x[r][7]=u1.w;
  }
}

__device__ __forceinline__ void megabar(int* bar, int id) {
  __syncthreads();                 // drains vmcnt of all waves
  if (threadIdx.x == 0) {
    atomicAdd(&bar[id], 1);
    while (aloadi(&bar[id]) < 64) __builtin_amdgcn_s_sleep(2);
  }
  __syncthreads();
}

// ---------------- mega kernel: fused kmeans (64 blocks, spin barriers) + riders ----------------
__global__ __launch_bounds__(512) void k_mega(
    const float* __restrict__ h, const float* __restrict__ sq,
    const __hip_bfloat16* __restrict__ xb, int* __restrict__ m1,
    const float* __restrict__ t2,
    int* __restrict__ bviA, int* __restrict__ biA,
    int* __restrict__ bviB, int* __restrict__ biB,
    float* __restrict__ tmpart, float* __restrict__ kvp, int* __restrict__ kip,
    float* __restrict__ psT, float* __restrict__ pcT, float* __restrict__ centsG,
    int* __restrict__ bar,
    const __hip_bfloat16* __restrict__ WbT, float* __restrict__ Wh,
    __hip_bfloat16* __restrict__ WhbT) {
  __shared__ __align__(16) char smem[55552];
  int bid = blockIdx.x;
  if (bid >= 96) { gram_role(xb, sq, m1, bid - 96, smem); return; }
  if (bid >= 64) { whmm_role(xb, WbT, Wh, WhbT, bid - 64); return; }

  float* wsum  = (float*)smem;               // 49152 B
  float* cents = (float*)(smem + 49152);     // 6144 B
  float* rv    = (float*)(smem + 55296);     // 8
  int*   ri    = (int*)(smem + 55328);       // 8
  float* wcnt  = (float*)(smem + 55360);     // 24
  float* cntB  = (float*)(smem + 55456);     // 3

  int t = threadIdx.x, lane = t & 63, wid = t >> 6, b = bid;
  int rbase = b * 64 + wid * 8;
  float x[8][8], sqr[8];
  load_rows(h, rbase, lane, x);
  #pragma unroll
  for (int r = 0; r < 8; ++r) sqr[r] = sq[rbase + r];

  float dloc[8];
  int b1, b2;

  // ===== fp0: c = h[0] =====
  {
    float cr[8];
    const float4* cp = (const float4*)h;
    float4 u0 = cp[2 * lane], u1 = cp[2 * lane + 1];
    cr[0]=u0.x;cr[1]=u0.y;cr[2]=u0.z;cr[3]=u0.w;cr[4]=u1.x;cr[5]=u1.y;cr[6]=u1.z;cr[7]=u1.w;
    float s0 = 0.f;
    #pragma unroll
    for (int q = 0; q < 8; ++q) s0 = fmaf(cr[q], cr[q], s0);
    float dd[8];
    #pragma unroll
    for (int r = 0; r < 8; ++r) dd[r] = 0.f;
    #pragma unroll
    for (int r = 0; r < 8; ++r)
      #pragma unroll
      for (int q = 0; q < 8; ++q) dd[r] = fmaf(x[r][q], cr[q], dd[r]);
    #pragma unroll
    for (int mm = 1; mm < 64; mm <<= 1) {
      s0 += __shfl_xor(s0, mm);
      #pragma unroll
      for (int r = 0; r < 8; ++r) dd[r] += __shfl_xor(dd[r], mm);
    }
    float bv = -1.f; int bi = 0;
    #pragma unroll
    for (int r = 0; r < 8; ++r) {
      float d = sqr[r] + s0 - 2.f * dd[r];
      dloc[r] = d;
      if (d > bv) { bv = d; bi = rbase + r; }
    }
    if (lane == 0) { rv[wid] = bv; ri[wid] = bi; }
  }
  __syncthreads();
  if (t == 0) {
    float vv = rv[0]; int ii = ri[0];
    for (int w = 1; w < 8; ++w)
      if (rv[w] > vv || (rv[w] == vv && ri[w] < ii)) { vv = rv[w]; ii = ri[w]; }
    int o1 = atomicExch(&bviA[b], __float_as_int(vv));
    int o2 = atomicExch(&biA[b], ii);
    asm volatile("" :: "v"(o1), "v"(o2));
    atomicAdd(&bar[0], 1);
  }
  // side partials during spin
  if (wid == 1) {
    #pragma unroll
    for (int c = 0; c < 3; ++c) {
      float m = fabsf(t2[c * NPTS + b * 64 + lane]);
      #pragma unroll
      for (int mm = 1; mm < 64; mm <<= 1) m = fmaxf(m, __shfl_xor(m, mm));
      if (lane == 0) tmpart[b * 3 + c] = m;
    }
  } else if (wid == 2) {
    int k = b * 64 + lane;
    float v = t2[k] + t2[NPTS + k] + t2[2 * NPTS + k];
    int ki = k;
    #pragma unroll
    for (int mm = 1; mm < 64; mm <<= 1) {
      float ov = __shfl_xor(v, mm); int oi = __shfl_xor(ki, mm);
      if (ov < v || (ov == v && oi < ki)) { v = ov; ki = oi; }
    }
    if (lane == 0) { kvp[b] = v; kip[b] = ki; }
  }
  if (t == 0) { while (aloadi(&bar[0]) < 64) __builtin_amdgcn_s_sleep(2); }
  __syncthreads();
  {
    float v = __int_as_float(aloadi(&bviA[lane]));
    int i = aloadi(&biA[lane]);
    #pragma unroll
    for (int mm = 1; mm < 64; mm <<= 1) {
      float ov = __shfl_xor(v, mm); int oi = __shfl_xor(i, mm);
      if (ov > v || (ov == v && oi < i)) { v = ov; i = oi; }
    }
    b1 = i;
  }

  // ===== fp1: c = h[b1] =====
  {
    float cr[8];
    const float4* cp = (const float4*)(h + (size_t)b1 * FIN);
    float4 u0 = cp[2 * lane], u1 = cp[2 * lane + 1];
    cr[0]=u0.x;cr[1]=u0.y;cr[2]=u0.z;cr[3]=u0.w;cr[4]=u1.x;cr[5]=u1.y;cr[6]=u1.z;cr[7]=u1.w;
    float s0 = 0.f;
    #pragma unroll
    for (int q = 0; q < 8; ++q) s0 = fmaf(cr[q], cr[q], s0);
    float dd[8];
    #pragma unroll
    for (int r = 0; r < 8; ++r) dd[r] = 0.f;
    #pragma unroll
    for (int r = 0; r < 8; ++r)
      #pragma unroll
      for (int q = 0; q < 8; ++q) dd[r] = fmaf(x[r][q], cr[q], dd[r]);
    #pragma unroll
    for (int mm = 1; mm < 64; mm <<= 1) {
      s0 += __shfl_xor(s0, mm);
      #pragma unroll
      for (int r = 0; r < 8; ++r) dd[r] += __shfl_xor(dd[r], mm);
    }
    float bv = -1.f; int bi = 0;
    #pragma unroll
    for (int r = 0; r < 8; ++r) {
      float d = fminf(sqr[r] + s0 - 2.f * dd[r], dloc[r]);
      dloc[r] = d;
      if (d > bv) { bv = d; bi = rbase + r; }
    }
    if (lane == 0) { rv[wid] = bv; ri[wid] = bi; }
  }
  __syncthreads();
  if (t == 0) {
    float vv = rv[0]; int ii = ri[0];
    for (int w = 1; w < 8; ++w)
      if (rv[w] > vv || (rv[w] == vv && ri[w] < ii)) { vv = rv[w]; ii = ri[w]; }
    int o1 = atomicExch(&bviB[b], __float_as_int(vv));
    int o2 = atomicExch(&biB[b], ii);
    asm volatile("" :: "v"(o1), "v"(o2));
    atomicAdd(&bar[1], 1);
    while (aloadi(&bar[1]) < 64) __builtin_amdgcn_s_sleep(2);
  }
  __syncthreads();
  {
    float v = __int_as_float(aloadi(&bviB[lane]));
    int i = aloadi(&biB[lane]);
    #pragma unroll
    for (int mm = 1; mm < 64; mm <<= 1) {
      float ov = __shfl_xor(v, mm); int oi = __shfl_xor(i, mm);
      if (ov > v || (ov == v && oi < i)) { v = ov; i = oi; }
    }
    b2 = i;
  }

  // ===== Lloyd x10 =====
  for (int it = 0; it < 10; ++it) {
    float c0r[8], c1r[8], c2r[8];
    if (it == 0) {
      const float4* p0 = (const float4*)h;
      const float4* p1 = (const float4*)(h + (size_t)b1 * FIN);
      const float4* p2 = (const float4*)(h + (size_t)b2 * FIN);
      float4 u;
      u = p0[2*lane];   c0r[0]=u.x;c0r[1]=u.y;c0r[2]=u.z;c0r[3]=u.w;
      u = p0[2*lane+1]; c0r[4]=u.x;c0r[5]=u.y;c0r[6]=u.z;c0r[7]=u.w;
      u = p1[2*lane];   c1r[0]=u.x;c1r[1]=u.y;c1r[2]=u.z;c1r[3]=u.w;
      u = p1[2*lane+1]; c1r[4]=u.x;c1r[5]=u.y;c1r[6]=u.z;c1r[7]=u.w;
      u = p2[2*lane];   c2r[0]=u.x;c2r[1]=u.y;c2r[2]=u.z;c2r[3]=u.w;
      u = p2[2*lane+1]; c2r[4]=u.x;c2r[5]=u.y;c2r[6]=u.z;c2r[7]=u.w;
    } else {
      float4 u;
      u = *(const float4*)&cents[8*lane];        c0r[0]=u.x;c0r[1]=u.y;c0r[2]=u.z;c0r[3]=u.w;
      u = *(const float4*)&cents[8*lane+4];      c0r[4]=u.x;c0r[5]=u.y;c0r[6]=u.z;c0r[7]=u.w;
      u = *(const float4*)&cents[512+8*lane];    c1r[0]=u.x;c1r[1]=u.y;c1r[2]=u.z;c1r[3]=u.w;
      u = *(const float4*)&cents[512+8*lane+4];  c1r[4]=u.x;c1r[5]=u.y;c1r[6]=u.z;c1r[7]=u.w;
      u = *(const float4*)&cents[1024+8*lane];   c2r[0]=u.x;c2r[1]=u.y;c2r[2]=u.z;c2r[3]=u.w;
      u = *(const float4*)&cents[1024+8*lane+4]; c2r[4]=u.x;c2r[5]=u.y;c2r[6]=u.z;c2r[7]=u.w;
    }
    float s0 = 0.f, s1 = 0.f, s2 = 0.f;
    #pragma unroll
    for (int q = 0; q < 8; ++q) {
      s0 = fmaf(c0r[q], c0r[q], s0); s1 = fmaf(c1r[q], c1r[q], s1); s2 = fmaf(c2r[q], c2r[q], s2);
    }
    #pragma unroll
    for (int mm = 1; mm < 64; mm <<= 1) {
      s0 += __shfl_xor(s0, mm); s1 += __shfl_xor(s1, mm); s2 += __shfl_xor(s2, mm);
    }
    float d[8][3];
    #pragma unroll
    for (int r = 0; r < 8; ++r) { d[r][0] = 0.f; d[r][1] = 0.f; d[r][2] = 0.f; }
    #pragma unroll
    for (int r = 0; r < 8; ++r)
      #pragma unroll
      for (int q = 0; q < 8; ++q) {
        d[r][0] = fmaf(x[r][q], c0r[q], d[r][0]);
        d[r][1] = fmaf(x[r][q], c1r[q], d[r][1]);
        d[r][2] = fmaf(x[r][q], c2r[q], d[r][2]);
      }
    #pragma unroll
    for (int mm = 1; mm < 64; mm <<= 1) {
      #pragma unroll
      for (int r = 0; r < 8; ++r) {
        d[r][0] += __shfl_xor(d[r][0], mm);
        d[r][1] += __shfl_xor(d[r][1], mm);
        d[r][2] += __shfl_xor(d[r][2], mm);
      }
    }
    float ps[3][8];
    #pragma unroll
    for (int c = 0; c < 3; ++c)
      #pragma unroll
      for (int q = 0; q < 8; ++q) ps[c][q] = 0.f;
    float cnt0 = 0.f, cnt1 = 0.f, cnt2 = 0.f;
    #pragma unroll
    for (int r = 0; r < 8; ++r) {
      float e0 = sqr[r] + s0 - 2.f * d[r][0];
      float e1 = sqr[r] + s1 - 2.f * d[r][1];
      float e2 = sqr[r] + s2 - 2.f * d[r][2];
      int bc = 0; float bd = e0;
      if (e1 < bd) { bd = e1; bc = 1; }
      if (e2 < bd) { bd = e2; bc = 2; }
      float f0 = bc == 0 ? 1.f : 0.f, f1 = bc == 1 ? 1.f : 0.f, f2 = bc == 2 ? 1.f : 0.f;
      #pragma unroll
      for (int q = 0; q < 8; ++q) {
        ps[0][q] = fmaf(f0, x[r][q], ps[0][q]);
        ps[1][q] = fmaf(f1, x[r][q], ps[1][q]);
        ps[2][q] = fmaf(f2, x[r][q], ps[2][q]);
      }
      cnt0 += f0; cnt1 += f1; cnt2 += f2;
    }
    #pragma unroll
    for (int c = 0; c < 3; ++c) {
      *(float4*)&wsum[wid * 1536 + c * 512 + 8 * lane]     = make_float4(ps[c][0], ps[c][1], ps[c][2], ps[c][3]);
      *(float4*)&wsum[wid * 1536 + c * 512 + 8 * lane + 4] = make_float4(ps[c][4], ps[c][5], ps[c][6], ps[c][7]);
    }
    if (lane == 0) { wcnt[wid * 3 + 0] = cnt0; wcnt[wid * 3 + 1] = cnt1; wcnt[wid * 3 + 2] = cnt2; }
    __syncthreads();
    // scatter block partial into its own column of psT[e][64]
    #pragma unroll
    for (int j = 0; j < 3; ++j) {
      int e = t + j * 512;
      float s = ((wsum[0*1536+e] + wsum[1*1536+e]) + (wsum[2*1536+e] + wsum[3*1536+e]))
              + ((wsum[4*1536+e] + wsum[5*1536+e]) + (wsum[6*1536+e] + wsum[7*1536+e]));
      axchf(&psT[(size_t)e * 64 + b], s);
    }
    if (t < 3) {
      float s = 0.f;
      for (int w = 0; w < 8; ++w) s += wcnt[w * 3 + t];
      axchf(&pcT[t * 64 + b], s);
    }
    megabar(bar, 2 + 2 * it);
    // stage A: reduce counts (all blocks) + own 24-row chunk -> centsG
    if (wid < 3) {
      float v = aloadf(&pcT[wid * 64 + lane]);
      v = wsum64(v);
      if (lane == 0) cntB[wid] = fmaxf(v, 1.f);
    }
    float rsum[3];
    #pragma unroll
    for (int j = 0; j < 3; ++j) {
      int e = 24 * b + wid * 3 + j;
      float v = aloadf(&psT[(size_t)e * 64 + lane]);
      rsum[j] = wsum64(v);
    }
    __syncthreads();   // cntB ready
    if (lane == 0) {
      #pragma unroll
      for (int j = 0; j < 3; ++j) {
        int e = 24 * b + wid * 3 + j;
        axchf(&centsG[e], rsum[j] / cntB[e >> 9]);
      }
    }
    if (it < 9) {
      megabar(bar, 3 + 2 * it);
      // stage B: read centsG into LDS
      for (int idx = t; idx < 1536; idx += 512) cents[idx] = aloadf(&centsG[idx]);
      __syncthreads();
    }
  }
}

// ---------------- mainC: centers/dc/tm + per-block d1v + softmax@Wh + out ----------------
__global__ __launch_bounds__(512) void k_mainC(
    const float* __restrict__ h, const float* __restrict__ sq,
    const float* __restrict__ t2, const __hip_bfloat16* __restrict__ WhbT,
    const float* __restrict__ Wh, const int* __restrict__ m1,
    const float* __restrict__ centsG,
    const float* __restrict__ tmpart, const float* __restrict__ kvp,
    const int* __restrict__ kip, float* __restrict__ out) {
  __shared__ float t2s[3 * 4096];
  __shared__ float VcS[8][16][68];
  __shared__ float SpS[8][16];
  __shared__ float Mrow[16];
  __shared__ float a012[16][3];
  __shared__ float cents[1536];
  __shared__ float tmS[3];
  __shared__ float red[8];
  __shared__ int skstar;
  int t = threadIdx.x, lane = t & 63, wid = t >> 6;
  int R0 = blockIdx.x * 16;
  for (int idx = t; idx < 3072; idx += 512)
    ((f32x4*)t2s)[idx] = ((const f32x4*)t2)[idx];
  if (t < 3) {
    float m = 0.f;
    for (int q = 0; q < 64; ++q) m = fmaxf(m, tmpart[q * 3 + t]);
    tmS[t] = m;
  }
  float sdc = 0.f;
  #pragma unroll
  for (int q = 0; q < 8; ++q)
    sdc += sqrtf(fmaxf(__int_as_float(m1[t + 512 * q]), 0.f));
  sdc = wsum64(sdc);
  if (lane == 0) red[wid] = sdc;
  for (int idx = t; idx < 1536; idx += 512) cents[idx] = centsG[idx];
  __syncthreads();
  float dcv = (((red[0] + red[1]) + (red[2] + red[3])) + ((red[4] + red[5]) + (red[6] + red[7])))
            * (1.f / (float)NPTS);
  {
    float c0r[8], c1r[8], c2r[8];
    float4 u;
    u = *(const float4*)&cents[8 * lane];          c0r[0]=u.x;c0r[1]=u.y;c0r[2]=u.z;c0r[3]=u.w;
    u = *(const float4*)&cents[8 * lane + 4];      c0r[4]=u.x;c0r[5]=u.y;c0r[6]=u.z;c0r[7]=u.w;
    u = *(const float4*)&cents[512 + 8 * lane];    c1r[0]=u.x;c1r[1]=u.y;c1r[2]=u.z;c1r[3]=u.w;
    u = *(const float4*)&cents[512 + 8 * lane + 4];c1r[4]=u.x;c1r[5]=u.y;c1r[6]=u.z;c1r[7]=u.w;
    u = *(const float4*)&cents[1024 + 8 * lane];   c2r[0]=u.x;c2r[1]=u.y;c2r[2]=u.z;c2r[3]=u.w;
    u = *(const float4*)&cents[1024 + 8*lane + 4]; c2r[4]=u.x;c2r[5]=u.y;c2r[6]=u.z;c2r[7]=u.w;
    float s0 = 0.f, s1 = 0.f, s2 = 0.f;
    #pragma unroll
    for (int q = 0; q < 8; ++q) {
      s0 = fmaf(c0r[q], c0r[q], s0); s1 = fmaf(c1r[q], c1r[q], s1); s2 = fmaf(c2r[q], c2r[q], s2);
    }
    float xr2[2][8];
    #pragma unroll
    for (int rr = 0; rr < 2; ++rr) {
      int row = R0 + 2 * wid + rr;
      const float4* xr = (const float4*)(h + (size_t)row * FIN);
      float4 u0 = xr[2 * lane], u1 = xr[2 * lane + 1];
      xr2[rr][0]=u0.x; xr2[rr][1]=u0.y; xr2[rr][2]=u0.z; xr2[rr][3]=u0.w;
      xr2[rr][4]=u1.x; xr2[rr][5]=u1.y; xr2[rr][6]=u1.z; xr2[rr][7]=u1.w;
    }
    float dd[2][3];
    #pragma unroll
    for (int rr = 0; rr < 2; ++rr) { dd[rr][0]=0.f; dd[rr][1]=0.f; dd[rr][2]=0.f; }
    #pragma unroll
    for (int rr = 0; rr < 2; ++rr)
      #pragma unroll
      for (int q = 0; q < 8; ++q) {
        dd[rr][0] = fmaf(xr2[rr][q], c0r[q], dd[rr][0]);
        dd[rr][1] = fmaf(xr2[rr][q], c1r[q], dd[rr][1]);
        dd[rr][2] = fmaf(xr2[rr][q], c2r[q], dd[rr][2]);
      }
    #pragma unroll
    for (int mm = 1; mm < 64; mm <<= 1) {
      s0 += __shfl_xor(s0, mm); s1 += __shfl_xor(s1, mm); s2 += __shfl_xor(s2, mm);
      #pragma unroll
      for (int rr = 0; rr < 2; ++rr) {
        dd[rr][0] += __shfl_xor(dd[rr][0], mm);
        dd[rr][1] += __shfl_xor(dd[rr][1], mm);
        dd[rr][2] += __shfl_xor(dd[rr][2], mm);
      }
    }
    if (lane == 0) {
      #pragma unroll
      for (int rr = 0; rr < 2; ++rr) {
        int row = R0 + 2 * wid + rr;
        float sr = sq[row];
        float q0 = sqrtf(fmaxf(sr + s0 - 2.f * dd[rr][0], 0.f));
        float q1 = sqrtf(fmaxf(sr + s1 - 2.f * dd[rr][1], 0.f));
        float q2 = sqrtf(fmaxf(sr + s2 - 2.f * dd[rr][2], 0.f));
        float nr = q1;
        float a0 = (q0 != 0.f) ? (dcv * nr / (q0 * q0)) : 0.f;
        float a1 = (q1 != 0.f) ? (dcv * nr / (q1 * q1)) : 0.f;
        float a2 = (q2 != 0.f) ? (dcv * nr / (q2 * q2)) : 0.f;
        a012[2 * wid + rr][0] = a0; a012[2 * wid + rr][1] = a1; a012[2 * wid + rr][2] = a2;
        Mrow[2 * wid + rr] = fmaf(fabsf(a2), tmS[2], fmaf(fabsf(a1), tmS[1], fabsf(a0) * tmS[0]));
      }
    }
  }
  __syncthreads();
  int r16 = lane & 15, hi = lane >> 4;
  float a0 = a012[r16][0], a1 = a012[r16][1], a2 = a012[r16][2];
  float M = Mrow[r16];
  int K0 = wid * 512;
  f32x4 acc[4];
  #pragma unroll
  for (int fn = 0; fn < 4; ++fn) acc[fn] = (f32x4){0.f, 0.f, 0.f, 0.f};
  float Sp = 0.f;
  const __hip_bfloat16* bwB[4];
  #pragma unroll
  for (int fn = 0; fn < 4; ++fn)
    bwB[fn] = WhbT + (size_t)(fn * 16 + r16) * NPTS + K0 + hi * 8;

  for (int kst = 0; kst < 16; ++kst) {
    int kb = K0 + kst * 32 + hi * 8;
    f32x4 c0a = *(const f32x4*)&t2s[kb],        c0b = *(const f32x4*)&t2s[kb + 4];
    f32x4 c1a = *(const f32x4*)&t2s[4096 + kb], c1b = *(const f32x4*)&t2s[4096 + kb + 4];
    f32x4 c2a = *(const f32x4*)&t2s[8192 + kb], c2b = *(const f32x4*)&t2s[8192 + kb + 4];
    float pv[8];
    #pragma unroll
    for (int j = 0; j < 4; ++j) {
      float L  = fmaf(a0, c0a[j], fmaf(a1, c1a[j], fmaf(a2, c2a[j], -M)));
      pv[j] = __expf(L);
      float L2 = fmaf(a0, c0b[j], fmaf(a1, c1b[j], fmaf(a2, c2b[j], -M)));
      pv[4 + j] = __expf(L2);
    }
    Sp += ((pv[0] + pv[1]) + (pv[2] + pv[3])) + ((pv[4] + pv[5]) + (pv[6] + pv[7]));
    union { bf16x8 v; __hip_bfloat162 h2[4]; } pa;
    #pragma unroll
    for (int jj = 0; jj < 4; ++jj) {
      float2 f2; f2.x = pv[2 * jj]; f2.y = pv[2 * jj + 1];
      pa.h2[jj] = __float22bfloat162_rn(f2);
    }
    #pragma unroll
    for (int fn = 0; fn < 4; ++fn) {
      bf16x8 bw = *(const bf16x8*)(bwB[fn] + kst * 32);
      acc[fn] = __builtin_amdgcn_mfma_f32_16x16x32_bf16(pa.v, bw, acc[fn], 0, 0, 0);
    }
  }
  Sp += __shfl_xor(Sp, 16);
  Sp += __shfl_xor(Sp, 32);
  if (hi == 0) SpS[wid][r16] = Sp;
  #pragma unroll
  for (int fn = 0; fn < 4; ++fn)
    #pragma unroll
    for (int q = 0; q < 4; ++q)
      VcS[wid][hi * 4 + q][fn * 16 + r16] = acc[fn][q];
  __syncthreads();
  for (int e = t; e < 1024; e += 512) {
    int row = e >> 6, col = e & 63;
    float V = 0.f;
    #pragma unroll
    for (int w = 0; w < 8; ++w) V += VcS[w][row][col];
    float S = 3.f * __expf(-Mrow[row]);
    #pragma unroll
    for (int w = 0; w < 8; ++w) S += SpS[w][row];
    float o = V / S;
    out[(size_t)(R0 + row) * FOUT + col] = o > 0.f ? o : expm1f(o);
  }
  if (blockIdx.x == 0) {
    if (wid == 0) {
      float v = kvp[lane]; int i = kip[lane];
      #pragma unroll
      for (int mm = 1; mm < 64; mm <<= 1) {
        float ov = __shfl_xor(v, mm); int oi = __shfl_xor(i, mm);
        if (ov < v || (ov == v && oi < i)) { v = ov; i = oi; }
      }
      if (lane == 0) skstar = i;
    }
    __syncthreads();
    int kstar = skstar;
    if (t < 192) {
      int c = t >> 6, j = t & 63;
      float wv = Wh[(size_t)kstar * FOUT + j];
      out[(size_t)(NPTS + c) * FOUT + j] = wv > 0.f ? wv : expm1f(wv);
    }
  }
}

extern "C" void kernel_launch(void* const* d_in, const int* in_sizes, int n_in,
                              void* d_out, int out_size, void* d_ws, size_t ws_size,
                              hipStream_t stream) {
  const float* h  = (const float*)d_in[0];
  const float* W  = (const float*)d_in[2];
  const float* t2 = (const float*)d_in[5];
  float* out = (float*)d_out;

  char* ws = (char*)d_ws;
  __hip_bfloat16* xb = (__hip_bfloat16*)ws;
  float* F = (float*)(ws + (size_t)NPTS * FIN * 2);
  float* sq   = F + 0;
  int*   m1   = (int*)(F + 4096);
  float* Wh   = F + 32768;
  __hip_bfloat16* WhbT = (__hip_bfloat16*)(F + 1756672);
  __hip_bfloat16* WbT  = (__hip_bfloat16*)(F + 1887744);
  float* G = F + 1904128;
  int*   bviA   = (int*)(G + 0);
  int*   biA    = (int*)(G + 64);
  int*   bviB   = (int*)(G + 128);
  int*   biB    = (int*)(G + 192);
  float* tmpart = G + 384;
  float* kvp    = G + 576;
  int*   kip    = (int*)(G + 640);
  int*   bar    = (int*)(G + 704);   // 32 ints
  float* centsG = G + 768;           // 1536
  float* pcT    = G + 2304;          // 3*64
  float* psT    = G + 2560;          // 1536*64

  k_prep<<<1027, 256, 0, stream>>>(h, W, xb, sq, m1, WbT, bar);
  k_mega<<<624, 512, 0, stream>>>(h, sq, xb, m1, t2, bviA, biA, bviB, biB,
                                  tmpart, kvp, kip, psT, pcT, centsG, bar, WbT, Wh, WhbT);
  k_mainC<<<256, 512, 0, stream>>>(h, sq, t2, WhbT, Wh, m1, centsG,
                                   tmpart, kvp, kip, out);
}

// Round 12
// 167.948 us; speedup vs baseline: 1.2861x; 1.2861x over previous
//
#include <hip/hip_runtime.h>
#include <hip/hip_bf16.h>
#include <math.h>

#define NPTS 4096
#define FIN 512
#define FOUT 64
#define SCALE 4194304.0f            // 2^22
#define INVSCALE 2.384185791015625e-7f

typedef __attribute__((ext_vector_type(8))) short bf16x8;
typedef __attribute__((ext_vector_type(4))) float f32x4;
typedef unsigned long long ull;

static __device__ __forceinline__ unsigned short bfbits(float x) {
  __hip_bfloat16 b = __float2bfloat16(x);
  return *reinterpret_cast<unsigned short*>(&b);
}

static __device__ __forceinline__ float wsum64(float v) {
  #pragma unroll
  for (int mm = 1; mm < 64; mm <<= 1) v += __shfl_xor(v, mm);
  return v;
}

static __device__ __forceinline__ int aloadi(int* p) {
  return __hip_atomic_load(p, __ATOMIC_RELAXED, __HIP_MEMORY_SCOPE_AGENT);
}
static __device__ __forceinline__ ull aloadu(ull* p) {
  return __hip_atomic_load(p, __ATOMIC_RELAXED, __HIP_MEMORY_SCOPE_AGENT);
}

// ---------------- prep: bf16 h, row norms, m1 init; WbT; zero accum/cnt/bar ----------------
__global__ __launch_bounds__(256) void k_prep(const float* __restrict__ h,
    const float* __restrict__ W, __hip_bfloat16* __restrict__ xb,
    float* __restrict__ sq, int* __restrict__ m1, __hip_bfloat16* __restrict__ WbT,
    ull* __restrict__ accZ, int* __restrict__ cntZ, int* __restrict__ barZ) {
  int bid = blockIdx.x, t = threadIdx.x;
  if (bid >= 1026) {                 // zero accumulators: 60 blocks x 256 x 8 = 122880 ull
    int zidx = (bid - 1026) * 256 + t;   // 0..15359
    ull* p = accZ + (size_t)zidx * 8;
    #pragma unroll
    for (int j = 0; j < 8; ++j) p[j] = 0ull;
    if (bid == 1026) {
      if (t < 40) cntZ[t] = 0;
      if (t < 32) barZ[t] = 0;
    }
    return;
  }
  if (bid >= 1024) {                 // W -> WbT[n][k]
    int base = (bid - 1024) * 16384;
    for (int rep = 0; rep < 64; ++rep) {
      int e = base + rep * 256 + t;
      int n = e >> 9, k = e & 511;
      WbT[e] = __float2bfloat16(W[k * FOUT + n]);
    }
    return;
  }
  int lane = t & 63, wid = t >> 6;
  int row = bid * 4 + wid;
  const float4* hr = (const float4*)(h + (size_t)row * FIN);
  float4 a = hr[lane], b = hr[64 + lane];
  ushort4 pa = { bfbits(a.x), bfbits(a.y), bfbits(a.z), bfbits(a.w) };
  ushort4 pb = { bfbits(b.x), bfbits(b.y), bfbits(b.z), bfbits(b.w) };
  *(ushort4*)(xb + (size_t)row * FIN + 4 * lane) = pa;
  *(ushort4*)(xb + (size_t)row * FIN + 256 + 4 * lane) = pb;
  float s = a.x*a.x + a.y*a.y + a.z*a.z + a.w*a.w
          + b.x*b.x + b.y*b.y + b.z*b.z + b.w*b.w;
  s = wsum64(s);
  if (lane == 0) { sq[row] = s; m1[row] = 0x7F800000; }
}

// ---------------- gram full-tile role: 128x128, 256 active threads ----------------
__device__ __forceinline__ void gram_role(const __hip_bfloat16* __restrict__ xb,
    const float* __restrict__ sq, int* __restrict__ m1, int gb, char* smem) {
  bool act = threadIdx.x < 256;
  int tid = threadIdx.x;
  int lane = tid & 63, wid = tid >> 6;
  int b = gb, I = 0;
  while (b >= 32 - I) { b -= 32 - I; ++I; }
  int J = I + b;
  char* As = smem;
  char* Bs = smem + 16384;

  int R0 = I * 128, C0 = J * 128;
  int rowBase = (wid >> 1) * 64;
  int colBase = (wid & 1) * 64;
  int lrow = lane & 15, hi = lane >> 4, rsub = hi * 4;

  f32x4 acc[4][4];
  #pragma unroll
  for (int p = 0; p < 4; ++p)
    #pragma unroll
    for (int q = 0; q < 4; ++q)
      acc[p][q] = (f32x4){0.f, 0.f, 0.f, 0.f};

  int srow = lane >> 3;
  int scol = ((lane & 7) ^ srow) * 8;
  const __hip_bfloat16* gA = xb + (size_t)(R0 + (wid & 3) * 32 + srow) * FIN + scol;
  const __hip_bfloat16* gB = xb + (size_t)(C0 + (wid & 3) * 32 + srow) * FIN + scol;
  char* lA = As + (wid & 3) * 4096;
  char* lB = Bs + (wid & 3) * 4096;
  int rdswz = (lrow & 7) << 4;

  for (int kt = 0; kt < 8; ++kt) {
    int K0 = kt * 64;
    if (act) {
      #pragma unroll
      for (int j = 0; j < 4; ++j) {
        __builtin_amdgcn_global_load_lds(
            (const __attribute__((address_space(1))) unsigned int*)(gA + (size_t)(8 * j) * FIN + K0),
            (__attribute__((address_space(3))) unsigned int*)(lA + j * 1024), 16, 0, 0);
        __builtin_amdgcn_global_load_lds(
            (const __attribute__((address_space(1))) unsigned int*)(gB + (size_t)(8 * j) * FIN + K0),
            (__attribute__((address_space(3))) unsigned int*)(lB + j * 1024), 16, 0, 0);
      }
    }
    __syncthreads();
    if (act) {
      #pragma unroll
      for (int s = 0; s < 2; ++s) {
        int k0b = s * 64;
        bf16x8 av[4], bw[4];
        #pragma unroll
        for (int f = 0; f < 4; ++f) {
          int arow = rowBase + f * 16 + lrow;
          av[f] = *(const bf16x8*)(As + arow * 128 + ((k0b + hi * 16) ^ rdswz));
          int brow = colBase + f * 16 + lrow;
          bw[f] = *(const bf16x8*)(Bs + brow * 128 + ((k0b + hi * 16) ^ rdswz));
        }
        #pragma unroll
        for (int fi = 0; fi < 4; ++fi)
          #pragma unroll
          for (int fj = 0; fj < 4; ++fj)
            acc[fi][fj] = __builtin_amdgcn_mfma_f32_16x16x32_bf16(av[fi], bw[fj], acc[fi][fj], 0, 0, 0);
      }
    }
    __syncthreads();
  }
  if (!act) return;

  int rowBaseG = R0 + rowBase, colBaseG = C0 + colBase;
  float sqr[16], sqc4[4];
  #pragma unroll
  for (int fi = 0; fi < 4; ++fi)
    #pragma unroll
    for (int rg = 0; rg < 4; ++rg)
      sqr[fi * 4 + rg] = sq[rowBaseG + fi * 16 + rsub + rg];
  #pragma unroll
  for (int fj = 0; fj < 4; ++fj) sqc4[fj] = sq[colBaseG + fj * 16 + lrow];

  float rmin[16], cmin[4];
  #pragma unroll
  for (int q = 0; q < 16; ++q) rmin[q] = INFINITY;
  #pragma unroll
  for (int q = 0; q < 4; ++q) cmin[q] = INFINITY;

  #pragma unroll
  for (int fi = 0; fi < 4; ++fi)
    #pragma unroll
    for (int fj = 0; fj < 4; ++fj)
      #pragma unroll
      for (int rg = 0; rg < 4; ++rg) {
        int r = rowBaseG + fi * 16 + rsub + rg;
        int c = colBaseG + fj * 16 + lrow;
        float d2 = sqr[fi * 4 + rg] + sqc4[fj] - 2.f * acc[fi][fj][rg];
        if (r == c) d2 = INFINITY;
        rmin[fi * 4 + rg] = fminf(rmin[fi * 4 + rg], d2);
        cmin[fj] = fminf(cmin[fj], d2);
      }

  #pragma unroll
  for (int mm = 1; mm < 16; mm <<= 1) {
    #pragma unroll
    for (int q = 0; q < 16; ++q) rmin[q] = fminf(rmin[q], __shfl_xor(rmin[q], mm));
  }
  if ((lane & 15) == 0) {
    #pragma unroll
    for (int q = 0; q < 16; ++q) {
      int r = rowBaseG + (q >> 2) * 16 + rsub + (q & 3);
      atomicMin(&m1[r], __float_as_int(rmin[q]));
    }
  }
  if (I != J) {
    #pragma unroll
    for (int mm = 16; mm < 64; mm <<= 1) {
      #pragma unroll
      for (int q = 0; q < 4; ++q) cmin[q] = fminf(cmin[q], __shfl_xor(cmin[q], mm));
    }
    if ((lane >> 4) == 0) {
      #pragma unroll
      for (int q = 0; q < 4; ++q)
        atomicMin(&m1[colBaseG + q * 16 + lane], __float_as_int(cmin[q]));
    }
  }
}

// ---------------- Wh = xb @ WbT^T via MFMA; also writes WhbT (transposed bf16) ----------------
__device__ __forceinline__ void whmm_role(const __hip_bfloat16* __restrict__ xb,
    const __hip_bfloat16* __restrict__ WbT, float* __restrict__ Wh,
    __hip_bfloat16* __restrict__ WhbT, int wb) {
  int t = threadIdx.x, lane = t & 63, wid = t >> 6;
  int r16 = lane & 15, hi = lane >> 4;
  int rbase = wb * 128 + wid * 16;
  f32x4 acc[4];
  #pragma unroll
  for (int fn = 0; fn < 4; ++fn) acc[fn] = (f32x4){0.f, 0.f, 0.f, 0.f};
  const __hip_bfloat16* aP = xb + (size_t)(rbase + r16) * FIN + hi * 8;
  const __hip_bfloat16* bP[4];
  #pragma unroll
  for (int fn = 0; fn < 4; ++fn)
    bP[fn] = WbT + (size_t)(fn * 16 + r16) * FIN + hi * 8;
  #pragma unroll
  for (int kk = 0; kk < 16; ++kk) {
    bf16x8 a = *(const bf16x8*)(aP + kk * 32);
    #pragma unroll
    for (int fn = 0; fn < 4; ++fn) {
      bf16x8 bw = *(const bf16x8*)(bP[fn] + kk * 32);
      acc[fn] = __builtin_amdgcn_mfma_f32_16x16x32_bf16(a, bw, acc[fn], 0, 0, 0);
    }
  }
  #pragma unroll
  for (int fn = 0; fn < 4; ++fn)
    #pragma unroll
    for (int q = 0; q < 4; ++q) {
      float v = acc[fn][q];
      Wh[(size_t)(rbase + hi * 4 + q) * FOUT + fn * 16 + r16] = v;
      WhbT[(size_t)(fn * 16 + r16) * NPTS + rbase + hi * 4 + q] = __float2bfloat16(v);
    }
}

// ---------------- row loader ----------------
__device__ __forceinline__ void load_rows(const float* __restrict__ h, int rbase,
    int lane, float x[8][8]) {
  #pragma unroll
  for (int r = 0; r < 8; ++r) {
    const float4* xr = (const float4*)(h + (size_t)(rbase + r) * FIN);
    float4 u0 = xr[2 * lane], u1 = xr[2 * lane + 1];
    x[r][0]=u0.x; x[r][1]=u0.y; x[r][2]=u0.z; x[r][3]=u0.w;
    x[r][4]=u1.x; x[r][5]=u1.y; x[r][6]=u1.z; x[r][7]=u1.w;
  }
}

__device__ __forceinline__ void megabar(int* bar, int id) {
  __syncthreads();                 // drains vmcnt of all waves
  if (threadIdx.x == 0) {
    atomicAdd(&bar[id], 1);
    while (aloadi(&bar[id]) < 64) __builtin_amdgcn_s_sleep(2);
  }
  __syncthreads();
}

// ---------------- mega kernel: fused kmeans (64 blocks, spin barriers) + riders ----------------
__global__ __launch_bounds__(512) void k_mega(
    const float* __restrict__ h, const float* __restrict__ sq,
    const __hip_bfloat16* __restrict__ xb, int* __restrict__ m1,
    const float* __restrict__ t2,
    int* __restrict__ bviA, int* __restrict__ biA,
    int* __restrict__ bviB, int* __restrict__ biB,
    float* __restrict__ tmpart, float* __restrict__ kvp, int* __restrict__ kip,
    ull* __restrict__ accum, int* __restrict__ cntAcc, int* __restrict__ bar,
    const __hip_bfloat16* __restrict__ WbT, float* __restrict__ Wh,
    __hip_bfloat16* __restrict__ WhbT) {
  __shared__ __align__(16) char smem[55552];
  int bid = blockIdx.x;
  if (bid >= 96) { gram_role(xb, sq, m1, bid - 96, smem); return; }
  if (bid >= 64) { whmm_role(xb, WbT, Wh, WhbT, bid - 64); return; }

  float* wsum  = (float*)smem;               // 49152 B
  float* cents = (float*)(smem + 49152);     // 6144 B
  float* rv    = (float*)(smem + 55296);     // 8
  int*   ri    = (int*)(smem + 55328);       // 8
  float* wcnt  = (float*)(smem + 55360);     // 24

  int t = threadIdx.x, lane = t & 63, wid = t >> 6, b = bid;
  int rbase = b * 64 + wid * 8;
  float x[8][8], sqr[8];
  load_rows(h, rbase, lane, x);
  #pragma unroll
  for (int r = 0; r < 8; ++r) sqr[r] = sq[rbase + r];

  float dloc[8];
  int b1, b2;

  // ===== fp0: c = h[0] =====
  {
    float cr[8];
    const float4* cp = (const float4*)h;
    float4 u0 = cp[2 * lane], u1 = cp[2 * lane + 1];
    cr[0]=u0.x;cr[1]=u0.y;cr[2]=u0.z;cr[3]=u0.w;cr[4]=u1.x;cr[5]=u1.y;cr[6]=u1.z;cr[7]=u1.w;
    float s0 = 0.f;
    #pragma unroll
    for (int q = 0; q < 8; ++q) s0 = fmaf(cr[q], cr[q], s0);
    float dd[8];
    #pragma unroll
    for (int r = 0; r < 8; ++r) dd[r] = 0.f;
    #pragma unroll
    for (int r = 0; r < 8; ++r)
      #pragma unroll
      for (int q = 0; q < 8; ++q) dd[r] = fmaf(x[r][q], cr[q], dd[r]);
    #pragma unroll
    for (int mm = 1; mm < 64; mm <<= 1) {
      s0 += __shfl_xor(s0, mm);
      #pragma unroll
      for (int r = 0; r < 8; ++r) dd[r] += __shfl_xor(dd[r], mm);
    }
    float bv = -1.f; int bi = 0;
    #pragma unroll
    for (int r = 0; r < 8; ++r) {
      float d = sqr[r] + s0 - 2.f * dd[r];
      dloc[r] = d;
      if (d > bv) { bv = d; bi = rbase + r; }
    }
    if (lane == 0) { rv[wid] = bv; ri[wid] = bi; }
  }
  __syncthreads();
  if (t == 0) {
    float vv = rv[0]; int ii = ri[0];
    for (int w = 1; w < 8; ++w)
      if (rv[w] > vv || (rv[w] == vv && ri[w] < ii)) { vv = rv[w]; ii = ri[w]; }
    int o1 = atomicExch(&bviA[b], __float_as_int(vv));
    int o2 = atomicExch(&biA[b], ii);
    asm volatile("" :: "v"(o1), "v"(o2));
    atomicAdd(&bar[0], 1);
  }
  // side partials during spin
  if (wid == 1) {
    #pragma unroll
    for (int c = 0; c < 3; ++c) {
      float m = fabsf(t2[c * NPTS + b * 64 + lane]);
      #pragma unroll
      for (int mm = 1; mm < 64; mm <<= 1) m = fmaxf(m, __shfl_xor(m, mm));
      if (lane == 0) tmpart[b * 3 + c] = m;
    }
  } else if (wid == 2) {
    int k = b * 64 + lane;
    float v = t2[k] + t2[NPTS + k] + t2[2 * NPTS + k];
    int ki = k;
    #pragma unroll
    for (int mm = 1; mm < 64; mm <<= 1) {
      float ov = __shfl_xor(v, mm); int oi = __shfl_xor(ki, mm);
      if (ov < v || (ov == v && oi < ki)) { v = ov; ki = oi; }
    }
    if (lane == 0) { kvp[b] = v; kip[b] = ki; }
  }
  if (t == 0) { while (aloadi(&bar[0]) < 64) __builtin_amdgcn_s_sleep(2); }
  __syncthreads();
  {
    float v = __int_as_float(aloadi(&bviA[lane]));
    int i = aloadi(&biA[lane]);
    #pragma unroll
    for (int mm = 1; mm < 64; mm <<= 1) {
      float ov = __shfl_xor(v, mm); int oi = __shfl_xor(i, mm);
      if (ov > v || (ov == v && oi < i)) { v = ov; i = oi; }
    }
    b1 = i;
  }

  // ===== fp1: c = h[b1] =====
  {
    float cr[8];
    const float4* cp = (const float4*)(h + (size_t)b1 * FIN);
    float4 u0 = cp[2 * lane], u1 = cp[2 * lane + 1];
    cr[0]=u0.x;cr[1]=u0.y;cr[2]=u0.z;cr[3]=u0.w;cr[4]=u1.x;cr[5]=u1.y;cr[6]=u1.z;cr[7]=u1.w;
    float s0 = 0.f;
    #pragma unroll
    for (int q = 0; q < 8; ++q) s0 = fmaf(cr[q], cr[q], s0);
    float dd[8];
    #pragma unroll
    for (int r = 0; r < 8; ++r) dd[r] = 0.f;
    #pragma unroll
    for (int r = 0; r < 8; ++r)
      #pragma unroll
      for (int q = 0; q < 8; ++q) dd[r] = fmaf(x[r][q], cr[q], dd[r]);
    #pragma unroll
    for (int mm = 1; mm < 64; mm <<= 1) {
      s0 += __shfl_xor(s0, mm);
      #pragma unroll
      for (int r = 0; r < 8; ++r) dd[r] += __shfl_xor(dd[r], mm);
    }
    float bv = -1.f; int bi = 0;
    #pragma unroll
    for (int r = 0; r < 8; ++r) {
      float d = fminf(sqr[r] + s0 - 2.f * dd[r], dloc[r]);
      dloc[r] = d;
      if (d > bv) { bv = d; bi = rbase + r; }
    }
    if (lane == 0) { rv[wid] = bv; ri[wid] = bi; }
  }
  __syncthreads();
  if (t == 0) {
    float vv = rv[0]; int ii = ri[0];
    for (int w = 1; w < 8; ++w)
      if (rv[w] > vv || (rv[w] == vv && ri[w] < ii)) { vv = rv[w]; ii = ri[w]; }
    int o1 = atomicExch(&bviB[b], __float_as_int(vv));
    int o2 = atomicExch(&biB[b], ii);
    asm volatile("" :: "v"(o1), "v"(o2));
    atomicAdd(&bar[1], 1);
    while (aloadi(&bar[1]) < 64) __builtin_amdgcn_s_sleep(2);
  }
  __syncthreads();
  {
    float v = __int_as_float(aloadi(&bviB[lane]));
    int i = aloadi(&biB[lane]);
    #pragma unroll
    for (int mm = 1; mm < 64; mm <<= 1) {
      float ov = __shfl_xor(v, mm); int oi = __shfl_xor(i, mm);
      if (ov > v || (ov == v && oi < i)) { v = ov; i = oi; }
    }
    b2 = i;
  }

  // ===== Lloyd x10 =====
  for (int it = 0; it < 10; ++it) {
    float c0r[8], c1r[8], c2r[8];
    if (it == 0) {
      const float4* p0 = (const float4*)h;
      const float4* p1 = (const float4*)(h + (size_t)b1 * FIN);
      const float4* p2 = (const float4*)(h + (size_t)b2 * FIN);
      float4 u;
      u = p0[2*lane];   c0r[0]=u.x;c0r[1]=u.y;c0r[2]=u.z;c0r[3]=u.w;
      u = p0[2*lane+1]; c0r[4]=u.x;c0r[5]=u.y;c0r[6]=u.z;c0r[7]=u.w;
      u = p1[2*lane];   c1r[0]=u.x;c1r[1]=u.y;c1r[2]=u.z;c1r[3]=u.w;
      u = p1[2*lane+1]; c1r[4]=u.x;c1r[5]=u.y;c1r[6]=u.z;c1r[7]=u.w;
      u = p2[2*lane];   c2r[0]=u.x;c2r[1]=u.y;c2r[2]=u.z;c2r[3]=u.w;
      u = p2[2*lane+1]; c2r[4]=u.x;c2r[5]=u.y;c2r[6]=u.z;c2r[7]=u.w;
    } else {
      ull* acc = accum + (size_t)(it - 1) * 8 * 1536;
      float cn[3];
      #pragma unroll
      for (int c = 0; c < 3; ++c)
        cn[c] = fmaxf((float)aloadi(&cntAcc[(it - 1) * 4 + c]), 1.f);
      for (int idx = t; idx < 1536; idx += 512) {
        long long ssum = 0;
        #pragma unroll
        for (int r = 0; r < 8; ++r) ssum += (long long)aloadu(&acc[r * 1536 + idx]);
        cents[idx] = (float)ssum * INVSCALE / cn[idx >> 9];
      }
      __syncthreads();
      float4 u;
      u = *(const float4*)&cents[8*lane];        c0r[0]=u.x;c0r[1]=u.y;c0r[2]=u.z;c0r[3]=u.w;
      u = *(const float4*)&cents[8*lane+4];      c0r[4]=u.x;c0r[5]=u.y;c0r[6]=u.z;c0r[7]=u.w;
      u = *(const float4*)&cents[512+8*lane];    c1r[0]=u.x;c1r[1]=u.y;c1r[2]=u.z;c1r[3]=u.w;
      u = *(const float4*)&cents[512+8*lane+4];  c1r[4]=u.x;c1r[5]=u.y;c1r[6]=u.z;c1r[7]=u.w;
      u = *(const float4*)&cents[1024+8*lane];   c2r[0]=u.x;c2r[1]=u.y;c2r[2]=u.z;c2r[3]=u.w;
      u = *(const float4*)&cents[1024+8*lane+4]; c2r[4]=u.x;c2r[5]=u.y;c2r[6]=u.z;c2r[7]=u.w;
    }
    float s0 = 0.f, s1 = 0.f, s2 = 0.f;
    #pragma unroll
    for (int q = 0; q < 8; ++q) {
      s0 = fmaf(c0r[q], c0r[q], s0); s1 = fmaf(c1r[q], c1r[q], s1); s2 = fmaf(c2r[q], c2r[q], s2);
    }
    #pragma unroll
    for (int mm = 1; mm < 64; mm <<= 1) {
      s0 += __shfl_xor(s0, mm); s1 += __shfl_xor(s1, mm); s2 += __shfl_xor(s2, mm);
    }
    float d[8][3];
    #pragma unroll
    for (int r = 0; r < 8; ++r) { d[r][0] = 0.f; d[r][1] = 0.f; d[r][2] = 0.f; }
    #pragma unroll
    for (int r = 0; r < 8; ++r)
      #pragma unroll
      for (int q = 0; q < 8; ++q) {
        d[r][0] = fmaf(x[r][q], c0r[q], d[r][0]);
        d[r][1] = fmaf(x[r][q], c1r[q], d[r][1]);
        d[r][2] = fmaf(x[r][q], c2r[q], d[r][2]);
      }
    #pragma unroll
    for (int mm = 1; mm < 64; mm <<= 1) {
      #pragma unroll
      for (int r = 0; r < 8; ++r) {
        d[r][0] += __shfl_xor(d[r][0], mm);
        d[r][1] += __shfl_xor(d[r][1], mm);
        d[r][2] += __shfl_xor(d[r][2], mm);
      }
    }
    float ps[3][8];
    #pragma unroll
    for (int c = 0; c < 3; ++c)
      #pragma unroll
      for (int q = 0; q < 8; ++q) ps[c][q] = 0.f;
    float cnt0 = 0.f, cnt1 = 0.f, cnt2 = 0.f;
    #pragma unroll
    for (int r = 0; r < 8; ++r) {
      float e0 = sqr[r] + s0 - 2.f * d[r][0];
      float e1 = sqr[r] + s1 - 2.f * d[r][1];
      float e2 = sqr[r] + s2 - 2.f * d[r][2];
      int bc = 0; float bd = e0;
      if (e1 < bd) { bd = e1; bc = 1; }
      if (e2 < bd) { bd = e2; bc = 2; }
      float f0 = bc == 0 ? 1.f : 0.f, f1 = bc == 1 ? 1.f : 0.f, f2 = bc == 2 ? 1.f : 0.f;
      #pragma unroll
      for (int q = 0; q < 8; ++q) {
        ps[0][q] = fmaf(f0, x[r][q], ps[0][q]);
        ps[1][q] = fmaf(f1, x[r][q], ps[1][q]);
        ps[2][q] = fmaf(f2, x[r][q], ps[2][q]);
      }
      cnt0 += f0; cnt1 += f1; cnt2 += f2;
    }
    #pragma unroll
    for (int c = 0; c < 3; ++c) {
      *(float4*)&wsum[wid * 1536 + c * 512 + 8 * lane]     = make_float4(ps[c][0], ps[c][1], ps[c][2], ps[c][3]);
      *(float4*)&wsum[wid * 1536 + c * 512 + 8 * lane + 4] = make_float4(ps[c][4], ps[c][5], ps[c][6], ps[c][7]);
    }
    if (lane == 0) { wcnt[wid * 3 + 0] = cnt0; wcnt[wid * 3 + 1] = cnt1; wcnt[wid * 3 + 2] = cnt2; }
    __syncthreads();
    ull* accO = accum + ((size_t)it * 8 + (b & 7)) * 1536;
    for (int idx = t; idx < 1536; idx += 512) {
      float s = ((wsum[0*1536+idx] + wsum[1*1536+idx]) + (wsum[2*1536+idx] + wsum[3*1536+idx]))
              + ((wsum[4*1536+idx] + wsum[5*1536+idx]) + (wsum[6*1536+idx] + wsum[7*1536+idx]));
      long long q = llrintf(s * SCALE);
      ull old = atomicAdd(&accO[idx], (ull)q);
      asm volatile("" :: "v"(old));
    }
    if (t < 3) {
      float s = 0.f;
      for (int w = 0; w < 8; ++w) s += wcnt[w * 3 + t];
      int old = atomicAdd(&cntAcc[it * 4 + t], (int)(s + 0.5f));
      asm volatile("" :: "v"(old));
    }
    if (it < 9) megabar(bar, 2 + it);
  }
}

// ---------------- mainC: centers/dc/tm + per-block d1v + softmax@Wh + out ----------------
__global__ __launch_bounds__(512) void k_mainC(
    const float* __restrict__ h, const float* __restrict__ sq,
    const float* __restrict__ t2, const __hip_bfloat16* __restrict__ WhbT,
    const float* __restrict__ Wh, const int* __restrict__ m1,
    const ull* __restrict__ accIn, const int* __restrict__ cntIn,
    const float* __restrict__ tmpart, const float* __restrict__ kvp,
    const int* __restrict__ kip, float* __restrict__ out) {
  __shared__ float t2s[3 * 4096];
  __shared__ float VcS[8][16][68];
  __shared__ float SpS[8][16];
  __shared__ float Mrow[16];
  __shared__ float a012[16][3];
  __shared__ float cents[1536];
  __shared__ float cntS[3];
  __shared__ float tmS[3];
  __shared__ float red[8];
  __shared__ int skstar;
  int t = threadIdx.x, lane = t & 63, wid = t >> 6;
  int R0 = blockIdx.x * 16;
  for (int idx = t; idx < 3072; idx += 512)
    ((f32x4*)t2s)[idx] = ((const f32x4*)t2)[idx];
  if (t < 3) {
    cntS[t] = fmaxf((float)cntIn[t], 1.f);
    float m = 0.f;
    for (int q = 0; q < 64; ++q) m = fmaxf(m, tmpart[q * 3 + t]);
    tmS[t] = m;
  }
  float sdc = 0.f;
  #pragma unroll
  for (int q = 0; q < 8; ++q)
    sdc += sqrtf(fmaxf(__int_as_float(m1[t + 512 * q]), 0.f));
  sdc = wsum64(sdc);
  if (lane == 0) red[wid] = sdc;
  __syncthreads();
  for (int idx = t; idx < 1536; idx += 512) {
    long long ssum = 0;
    #pragma unroll
    for (int r = 0; r < 8; ++r) ssum += (long long)accIn[r * 1536 + idx];
    cents[idx] = (float)ssum * INVSCALE / cntS[idx >> 9];
  }
  __syncthreads();
  float dcv = (((red[0] + red[1]) + (red[2] + red[3])) + ((red[4] + red[5]) + (red[6] + red[7])))
            * (1.f / (float)NPTS);
  {
    float c0r[8], c1r[8], c2r[8];
    float4 u;
    u = *(const float4*)&cents[8 * lane];          c0r[0]=u.x;c0r[1]=u.y;c0r[2]=u.z;c0r[3]=u.w;
    u = *(const float4*)&cents[8 * lane + 4];      c0r[4]=u.x;c0r[5]=u.y;c0r[6]=u.z;c0r[7]=u.w;
    u = *(const float4*)&cents[512 + 8 * lane];    c1r[0]=u.x;c1r[1]=u.y;c1r[2]=u.z;c1r[3]=u.w;
    u = *(const float4*)&cents[512 + 8 * lane + 4];c1r[4]=u.x;c1r[5]=u.y;c1r[6]=u.z;c1r[7]=u.w;
    u = *(const float4*)&cents[1024 + 8 * lane];   c2r[0]=u.x;c2r[1]=u.y;c2r[2]=u.z;c2r[3]=u.w;
    u = *(const float4*)&cents[1024 + 8*lane + 4]; c2r[4]=u.x;c2r[5]=u.y;c2r[6]=u.z;c2r[7]=u.w;
    float s0 = 0.f, s1 = 0.f, s2 = 0.f;
    #pragma unroll
    for (int q = 0; q < 8; ++q) {
      s0 = fmaf(c0r[q], c0r[q], s0); s1 = fmaf(c1r[q], c1r[q], s1); s2 = fmaf(c2r[q], c2r[q], s2);
    }
    float xr2[2][8];
    #pragma unroll
    for (int rr = 0; rr < 2; ++rr) {
      int row = R0 + 2 * wid + rr;
      const float4* xr = (const float4*)(h + (size_t)row * FIN);
      float4 u0 = xr[2 * lane], u1 = xr[2 * lane + 1];
      xr2[rr][0]=u0.x; xr2[rr][1]=u0.y; xr2[rr][2]=u0.z; xr2[rr][3]=u0.w;
      xr2[rr][4]=u1.x; xr2[rr][5]=u1.y; xr2[rr][6]=u1.z; xr2[rr][7]=u1.w;
    }
    float dd[2][3];
    #pragma unroll
    for (int rr = 0; rr < 2; ++rr) { dd[rr][0]=0.f; dd[rr][1]=0.f; dd[rr][2]=0.f; }
    #pragma unroll
    for (int rr = 0; rr < 2; ++rr)
      #pragma unroll
      for (int q = 0; q < 8; ++q) {
        dd[rr][0] = fmaf(xr2[rr][q], c0r[q], dd[rr][0]);
        dd[rr][1] = fmaf(xr2[rr][q], c1r[q], dd[rr][1]);
        dd[rr][2] = fmaf(xr2[rr][q], c2r[q], dd[rr][2]);
      }
    #pragma unroll
    for (int mm = 1; mm < 64; mm <<= 1) {
      s0 += __shfl_xor(s0, mm); s1 += __shfl_xor(s1, mm); s2 += __shfl_xor(s2, mm);
      #pragma unroll
      for (int rr = 0; rr < 2; ++rr) {
        dd[rr][0] += __shfl_xor(dd[rr][0], mm);
        dd[rr][1] += __shfl_xor(dd[rr][1], mm);
        dd[rr][2] += __shfl_xor(dd[rr][2], mm);
      }
    }
    if (lane == 0) {
      #pragma unroll
      for (int rr = 0; rr < 2; ++rr) {
        int row = R0 + 2 * wid + rr;
        float sr = sq[row];
        float q0 = sqrtf(fmaxf(sr + s0 - 2.f * dd[rr][0], 0.f));
        float q1 = sqrtf(fmaxf(sr + s1 - 2.f * dd[rr][1], 0.f));
        float q2 = sqrtf(fmaxf(sr + s2 - 2.f * dd[rr][2], 0.f));
        float nr = q1;
        float a0 = (q0 != 0.f) ? (dcv * nr / (q0 * q0)) : 0.f;
        float a1 = (q1 != 0.f) ? (dcv * nr / (q1 * q1)) : 0.f;
        float a2 = (q2 != 0.f) ? (dcv * nr / (q2 * q2)) : 0.f;
        a012[2 * wid + rr][0] = a0; a012[2 * wid + rr][1] = a1; a012[2 * wid + rr][2] = a2;
        Mrow[2 * wid + rr] = fmaf(fabsf(a2), tmS[2], fmaf(fabsf(a1), tmS[1], fabsf(a0) * tmS[0]));
      }
    }
  }
  __syncthreads();
  int r16 = lane & 15, hi = lane >> 4;
  float a0 = a012[r16][0], a1 = a012[r16][1], a2 = a012[r16][2];
  float M = Mrow[r16];
  int K0 = wid * 512;
  f32x4 acc[4];
  #pragma unroll
  for (int fn = 0; fn < 4; ++fn) acc[fn] = (f32x4){0.f, 0.f, 0.f, 0.f};
  float Sp = 0.f;
  const __hip_bfloat16* bwB[4];
  #pragma unroll
  for (int fn = 0; fn < 4; ++fn)
    bwB[fn] = WhbT + (size_t)(fn * 16 + r16) * NPTS + K0 + hi * 8;

  for (int kst = 0; kst < 16; ++kst) {
    int kb = K0 + kst * 32 + hi * 8;
    f32x4 c0a = *(const f32x4*)&t2s[kb],        c0b = *(const f32x4*)&t2s[kb + 4];
    f32x4 c1a = *(const f32x4*)&t2s[4096 + kb], c1b = *(const f32x4*)&t2s[4096 + kb + 4];
    f32x4 c2a = *(const f32x4*)&t2s[8192 + kb], c2b = *(const f32x4*)&t2s[8192 + kb + 4];
    float pv[8];
    #pragma unroll
    for (int j = 0; j < 4; ++j) {
      float L  = fmaf(a0, c0a[j], fmaf(a1, c1a[j], fmaf(a2, c2a[j], -M)));
      pv[j] = __expf(L);
      float L2 = fmaf(a0, c0b[j], fmaf(a1, c1b[j], fmaf(a2, c2b[j], -M)));
      pv[4 + j] = __expf(L2);
    }
    Sp += ((pv[0] + pv[1]) + (pv[2] + pv[3])) + ((pv[4] + pv[5]) + (pv[6] + pv[7]));
    union { bf16x8 v; __hip_bfloat162 h2[4]; } pa;
    #pragma unroll
    for (int jj = 0; jj < 4; ++jj) {
      float2 f2; f2.x = pv[2 * jj]; f2.y = pv[2 * jj + 1];
      pa.h2[jj] = __float22bfloat162_rn(f2);
    }
    #pragma unroll
    for (int fn = 0; fn < 4; ++fn) {
      bf16x8 bw = *(const bf16x8*)(bwB[fn] + kst * 32);
      acc[fn] = __builtin_amdgcn_mfma_f32_16x16x32_bf16(pa.v, bw, acc[fn], 0, 0, 0);
    }
  }
  Sp += __shfl_xor(Sp, 16);
  Sp += __shfl_xor(Sp, 32);
  if (hi == 0) SpS[wid][r16] = Sp;
  #pragma unroll
  for (int fn = 0; fn < 4; ++fn)
    #pragma unroll
    for (int q = 0; q < 4; ++q)
      VcS[wid][hi * 4 + q][fn * 16 + r16] = acc[fn][q];
  __syncthreads();
  for (int e = t; e < 1024; e += 512) {
    int row = e >> 6, col = e & 63;
    float V = 0.f;
    #pragma unroll
    for (int w = 0; w < 8; ++w) V += VcS[w][row][col];
    float S = 3.f * __expf(-Mrow[row]);
    #pragma unroll
    for (int w = 0; w < 8; ++w) S += SpS[w][row];
    float o = V / S;
    out[(size_t)(R0 + row) * FOUT + col] = o > 0.f ? o : expm1f(o);
  }
  if (blockIdx.x == 0) {
    if (wid == 0) {
      float v = kvp[lane]; int i = kip[lane];
      #pragma unroll
      for (int mm = 1; mm < 64; mm <<= 1) {
        float ov = __shfl_xor(v, mm); int oi = __shfl_xor(i, mm);
        if (ov < v || (ov == v && oi < i)) { v = ov; i = oi; }
      }
      if (lane == 0) skstar = i;
    }
    __syncthreads();
    int kstar = skstar;
    if (t < 192) {
      int c = t >> 6, j = t & 63;
      float wv = Wh[(size_t)kstar * FOUT + j];
      out[(size_t)(NPTS + c) * FOUT + j] = wv > 0.f ? wv : expm1f(wv);
    }
  }
}

extern "C" void kernel_launch(void* const* d_in, const int* in_sizes, int n_in,
                              void* d_out, int out_size, void* d_ws, size_t ws_size,
                              hipStream_t stream) {
  const float* h  = (const float*)d_in[0];
  const float* W  = (const float*)d_in[2];
  const float* t2 = (const float*)d_in[5];
  float* out = (float*)d_out;

  char* ws = (char*)d_ws;
  __hip_bfloat16* xb = (__hip_bfloat16*)ws;
  float* F = (float*)(ws + (size_t)NPTS * FIN * 2);
  float* sq   = F + 0;
  int*   m1   = (int*)(F + 4096);
  float* Wh   = F + 32768;
  __hip_bfloat16* WhbT = (__hip_bfloat16*)(F + 1756672);
  __hip_bfloat16* WbT  = (__hip_bfloat16*)(F + 1887744);
  float* G = F + 1904128;
  int*   bviA   = (int*)(G + 0);
  int*   biA    = (int*)(G + 64);
  int*   bviB   = (int*)(G + 128);
  int*   biB    = (int*)(G + 192);
  float* tmpart = G + 384;
  float* kvp    = G + 576;
  int*   kip    = (int*)(G + 640);
  int*   bar    = (int*)(G + 704);          // 32 ints
  ull*   accum  = (ull*)(G + 768);          // 10 * 8 * 1536 ull
  int*   cntAcc = (int*)(G + 768 + 245760); // 10 * 4 int

  k_prep<<<1086, 256, 0, stream>>>(h, W, xb, sq, m1, WbT, accum, cntAcc, bar);
  k_mega<<<624, 512, 0, stream>>>(h, sq, xb, m1, t2, bviA, biA, bviB, biB,
                                  tmpart, kvp, kip, accum, cntAcc, bar, WbT, Wh, WhbT);
  k_mainC<<<256, 512, 0, stream>>>(h, sq, t2, WhbT, Wh, m1,
                                   (const ull*)(accum + 9 * 8 * 1536), (const int*)(cntAcc + 9 * 4),
                                   tmpart, kvp, kip, out);
}

// Round 13
// 136.454 us; speedup vs baseline: 1.5829x; 1.2308x over previous
//
#include <hip/hip_runtime.h>
#include <hip/hip_bf16.h>
#include <math.h>

#define NPTS 4096
#define FIN 512
#define FOUT 64
#define SCALE 4194304.0f            // 2^22
#define INVSCALE 2.384185791015625e-7f

typedef __attribute__((ext_vector_type(8))) short bf16x8;
typedef __attribute__((ext_vector_type(4))) float f32x4;
typedef unsigned long long ull;

static __device__ __forceinline__ unsigned short bfbits(float x) {
  __hip_bfloat16 b = __float2bfloat16(x);
  return *reinterpret_cast<unsigned short*>(&b);
}

static __device__ __forceinline__ float wsum64(float v) {
  #pragma unroll
  for (int mm = 1; mm < 64; mm <<= 1) v += __shfl_xor(v, mm);
  return v;
}

static __device__ __forceinline__ int aloadi(int* p) {
  return __hip_atomic_load(p, __ATOMIC_RELAXED, __HIP_MEMORY_SCOPE_AGENT);
}
static __device__ __forceinline__ ull aloadu(ull* p) {
  return __hip_atomic_load(p, __ATOMIC_RELAXED, __HIP_MEMORY_SCOPE_AGENT);
}

// ---------------- prep: bf16 h, row norms, m1 init; WbT; zero accum/cnt/bar ----------------
__global__ __launch_bounds__(256) void k_prep(const float* __restrict__ h,
    const float* __restrict__ W, __hip_bfloat16* __restrict__ xb,
    float* __restrict__ sq, int* __restrict__ m1, __hip_bfloat16* __restrict__ WbT,
    ull* __restrict__ accZ, int* __restrict__ cntZ, int* __restrict__ barZ) {
  int bid = blockIdx.x, t = threadIdx.x;
  if (bid >= 1026) {                 // zero accumulators (6 blocks)
    int idx = (bid - 1026) * 256 + t;       // 0..1535
    #pragma unroll
    for (int s = 0; s < 10; ++s) accZ[s * 1536 + idx] = 0ull;
    if (idx < 40) cntZ[idx] = 0;
    if (idx < 32) barZ[idx] = 0;
    return;
  }
  if (bid >= 1024) {                 // W -> WbT[n][k]
    int base = (bid - 1024) * 16384;
    for (int rep = 0; rep < 64; ++rep) {
      int e = base + rep * 256 + t;
      int n = e >> 9, k = e & 511;
      WbT[e] = __float2bfloat16(W[k * FOUT + n]);
    }
    return;
  }
  int lane = t & 63, wid = t >> 6;
  int row = bid * 4 + wid;
  const float4* hr = (const float4*)(h + (size_t)row * FIN);
  float4 a = hr[lane], b = hr[64 + lane];
  ushort4 pa = { bfbits(a.x), bfbits(a.y), bfbits(a.z), bfbits(a.w) };
  ushort4 pb = { bfbits(b.x), bfbits(b.y), bfbits(b.z), bfbits(b.w) };
  *(ushort4*)(xb + (size_t)row * FIN + 4 * lane) = pa;
  *(ushort4*)(xb + (size_t)row * FIN + 256 + 4 * lane) = pb;
  float s = a.x*a.x + a.y*a.y + a.z*a.z + a.w*a.w
          + b.x*b.x + b.y*b.y + b.z*b.z + b.w*b.w;
  s = wsum64(s);
  if (lane == 0) { sq[row] = s; m1[row] = 0x7F800000; }
}

// ---------------- gram full-tile role: 128x128, 256 active threads ----------------
__device__ __forceinline__ void gram_role(const __hip_bfloat16* __restrict__ xb,
    const float* __restrict__ sq, int* __restrict__ m1, int gb, char* smem) {
  bool act = threadIdx.x < 256;
  int tid = threadIdx.x;
  int lane = tid & 63, wid = tid >> 6;
  int b = gb, I = 0;
  while (b >= 32 - I) { b -= 32 - I; ++I; }
  int J = I + b;
  char* As = smem;
  char* Bs = smem + 16384;

  int R0 = I * 128, C0 = J * 128;
  int rowBase = (wid >> 1) * 64;
  int colBase = (wid & 1) * 64;
  int lrow = lane & 15, hi = lane >> 4, rsub = hi * 4;

  f32x4 acc[4][4];
  #pragma unroll
  for (int p = 0; p < 4; ++p)
    #pragma unroll
    for (int q = 0; q < 4; ++q)
      acc[p][q] = (f32x4){0.f, 0.f, 0.f, 0.f};

  int srow = lane >> 3;
  int scol = ((lane & 7) ^ srow) * 8;
  const __hip_bfloat16* gA = xb + (size_t)(R0 + (wid & 3) * 32 + srow) * FIN + scol;
  const __hip_bfloat16* gB = xb + (size_t)(C0 + (wid & 3) * 32 + srow) * FIN + scol;
  char* lA = As + (wid & 3) * 4096;
  char* lB = Bs + (wid & 3) * 4096;
  int rdswz = (lrow & 7) << 4;

  for (int kt = 0; kt < 8; ++kt) {
    int K0 = kt * 64;
    if (act) {
      #pragma unroll
      for (int j = 0; j < 4; ++j) {
        __builtin_amdgcn_global_load_lds(
            (const __attribute__((address_space(1))) unsigned int*)(gA + (size_t)(8 * j) * FIN + K0),
            (__attribute__((address_space(3))) unsigned int*)(lA + j * 1024), 16, 0, 0);
        __builtin_amdgcn_global_load_lds(
            (const __attribute__((address_space(1))) unsigned int*)(gB + (size_t)(8 * j) * FIN + K0),
            (__attribute__((address_space(3))) unsigned int*)(lB + j * 1024), 16, 0, 0);
      }
    }
    __syncthreads();
    if (act) {
      #pragma unroll
      for (int s = 0; s < 2; ++s) {
        int k0b = s * 64;
        bf16x8 av[4], bw[4];
        #pragma unroll
        for (int f = 0; f < 4; ++f) {
          int arow = rowBase + f * 16 + lrow;
          av[f] = *(const bf16x8*)(As + arow * 128 + ((k0b + hi * 16) ^ rdswz));
          int brow = colBase + f * 16 + lrow;
          bw[f] = *(const bf16x8*)(Bs + brow * 128 + ((k0b + hi * 16) ^ rdswz));
        }
        #pragma unroll
        for (int fi = 0; fi < 4; ++fi)
          #pragma unroll
          for (int fj = 0; fj < 4; ++fj)
            acc[fi][fj] = __builtin_amdgcn_mfma_f32_16x16x32_bf16(av[fi], bw[fj], acc[fi][fj], 0, 0, 0);
      }
    }
    __syncthreads();
  }
  if (!act) return;

  int rowBaseG = R0 + rowBase, colBaseG = C0 + colBase;
  float sqr[16], sqc4[4];
  #pragma unroll
  for (int fi = 0; fi < 4; ++fi)
    #pragma unroll
    for (int rg = 0; rg < 4; ++rg)
      sqr[fi * 4 + rg] = sq[rowBaseG + fi * 16 + rsub + rg];
  #pragma unroll
  for (int fj = 0; fj < 4; ++fj) sqc4[fj] = sq[colBaseG + fj * 16 + lrow];

  float rmin[16], cmin[4];
  #pragma unroll
  for (int q = 0; q < 16; ++q) rmin[q] = INFINITY;
  #pragma unroll
  for (int q = 0; q < 4; ++q) cmin[q] = INFINITY;

  #pragma unroll
  for (int fi = 0; fi < 4; ++fi)
    #pragma unroll
    for (int fj = 0; fj < 4; ++fj)
      #pragma unroll
      for (int rg = 0; rg < 4; ++rg) {
        int r = rowBaseG + fi * 16 + rsub + rg;
        int c = colBaseG + fj * 16 + lrow;
        float d2 = sqr[fi * 4 + rg] + sqc4[fj] - 2.f * acc[fi][fj][rg];
        if (r == c) d2 = INFINITY;
        rmin[fi * 4 + rg] = fminf(rmin[fi * 4 + rg], d2);
        cmin[fj] = fminf(cmin[fj], d2);
      }

  #pragma unroll
  for (int mm = 1; mm < 16; mm <<= 1) {
    #pragma unroll
    for (int q = 0; q < 16; ++q) rmin[q] = fminf(rmin[q], __shfl_xor(rmin[q], mm));
  }
  if ((lane & 15) == 0) {
    #pragma unroll
    for (int q = 0; q < 16; ++q) {
      int r = rowBaseG + (q >> 2) * 16 + rsub + (q & 3);
      atomicMin(&m1[r], __float_as_int(rmin[q]));
    }
  }
  if (I != J) {
    #pragma unroll
    for (int mm = 16; mm < 64; mm <<= 1) {
      #pragma unroll
      for (int q = 0; q < 4; ++q) cmin[q] = fminf(cmin[q], __shfl_xor(cmin[q], mm));
    }
    if ((lane >> 4) == 0) {
      #pragma unroll
      for (int q = 0; q < 4; ++q)
        atomicMin(&m1[colBaseG + q * 16 + lane], __float_as_int(cmin[q]));
    }
  }
}

// ---------------- Wh = xb @ WbT^T via MFMA; also writes WhbT (transposed bf16) ----------------
__device__ __forceinline__ void whmm_role(const __hip_bfloat16* __restrict__ xb,
    const __hip_bfloat16* __restrict__ WbT, float* __restrict__ Wh,
    __hip_bfloat16* __restrict__ WhbT, int wb) {
  int t = threadIdx.x, lane = t & 63, wid = t >> 6;
  int r16 = lane & 15, hi = lane >> 4;
  int rbase = wb * 128 + wid * 16;
  f32x4 acc[4];
  #pragma unroll
  for (int fn = 0; fn < 4; ++fn) acc[fn] = (f32x4){0.f, 0.f, 0.f, 0.f};
  const __hip_bfloat16* aP = xb + (size_t)(rbase + r16) * FIN + hi * 8;
  const __hip_bfloat16* bP[4];
  #pragma unroll
  for (int fn = 0; fn < 4; ++fn)
    bP[fn] = WbT + (size_t)(fn * 16 + r16) * FIN + hi * 8;
  #pragma unroll
  for (int kk = 0; kk < 16; ++kk) {
    bf16x8 a = *(const bf16x8*)(aP + kk * 32);
    #pragma unroll
    for (int fn = 0; fn < 4; ++fn) {
      bf16x8 bw = *(const bf16x8*)(bP[fn] + kk * 32);
      acc[fn] = __builtin_amdgcn_mfma_f32_16x16x32_bf16(a, bw, acc[fn], 0, 0, 0);
    }
  }
  #pragma unroll
  for (int fn = 0; fn < 4; ++fn)
    #pragma unroll
    for (int q = 0; q < 4; ++q) {
      float v = acc[fn][q];
      Wh[(size_t)(rbase + hi * 4 + q) * FOUT + fn * 16 + r16] = v;
      WhbT[(size_t)(fn * 16 + r16) * NPTS + rbase + hi * 4 + q] = __float2bfloat16(v);
    }
}

// ---------------- row loader ----------------
__device__ __forceinline__ void load_rows(const float* __restrict__ h, int rbase,
    int lane, float x[8][8]) {
  #pragma unroll
  for (int r = 0; r < 8; ++r) {
    const float4* xr = (const float4*)(h + (size_t)(rbase + r) * FIN);
    float4 u0 = xr[2 * lane], u1 = xr[2 * lane + 1];
    x[r][0]=u0.x; x[r][1]=u0.y; x[r][2]=u0.z; x[r][3]=u0.w;
    x[r][4]=u1.x; x[r][5]=u1.y; x[r][6]=u1.z; x[r][7]=u1.w;
  }
}

__device__ __forceinline__ void megabar(int* bar, int id) {
  __syncthreads();                 // drains vmcnt of all waves (publishes complete)
  if (threadIdx.x == 0) {
    atomicAdd(&bar[id], 1);
    while (aloadi(&bar[id]) < 64) __builtin_amdgcn_s_sleep(2);
  }
  __syncthreads();
}

// ---------------- mega kernel: fused kmeans (64 blocks, spin barriers) + riders ----------------
__global__ __launch_bounds__(512) void k_mega(
    const float* __restrict__ h, const float* __restrict__ sq,
    const __hip_bfloat16* __restrict__ xb, int* __restrict__ m1,
    const float* __restrict__ t2,
    int* __restrict__ bviA, int* __restrict__ biA,
    int* __restrict__ bviB, int* __restrict__ biB,
    float* __restrict__ tmpart, float* __restrict__ kvp, int* __restrict__ kip,
    ull* __restrict__ accum, int* __restrict__ cntAcc, int* __restrict__ bar,
    const __hip_bfloat16* __restrict__ WbT, float* __restrict__ Wh,
    __hip_bfloat16* __restrict__ WhbT) {
  __shared__ __align__(16) char smem[55552];
  int bid = blockIdx.x;
  if (bid >= 96) { gram_role(xb, sq, m1, bid - 96, smem); return; }
  if (bid >= 64) { whmm_role(xb, WbT, Wh, WhbT, bid - 64); return; }

  float* wsum  = (float*)smem;               // 49152 B
  float* cents = (float*)(smem + 49152);     // 6144 B
  float* rv    = (float*)(smem + 55296);     // 8
  int*   ri    = (int*)(smem + 55328);       // 8
  float* wcnt  = (float*)(smem + 55360);     // 24

  int t = threadIdx.x, lane = t & 63, wid = t >> 6, b = bid;
  int rbase = b * 64 + wid * 8;
  float x[8][8], sqr[8];
  load_rows(h, rbase, lane, x);
  #pragma unroll
  for (int r = 0; r < 8; ++r) sqr[r] = sq[rbase + r];

  float dloc[8];
  int b1, b2;

  // ===== fp0: c = h[0] =====
  {
    float cr[8];
    const float4* cp = (const float4*)h;
    float4 u0 = cp[2 * lane], u1 = cp[2 * lane + 1];
    cr[0]=u0.x;cr[1]=u0.y;cr[2]=u0.z;cr[3]=u0.w;cr[4]=u1.x;cr[5]=u1.y;cr[6]=u1.z;cr[7]=u1.w;
    float s0 = 0.f;
    #pragma unroll
    for (int q = 0; q < 8; ++q) s0 = fmaf(cr[q], cr[q], s0);
    float dd[8];
    #pragma unroll
    for (int r = 0; r < 8; ++r) dd[r] = 0.f;
    #pragma unroll
    for (int r = 0; r < 8; ++r)
      #pragma unroll
      for (int q = 0; q < 8; ++q) dd[r] = fmaf(x[r][q], cr[q], dd[r]);
    #pragma unroll
    for (int mm = 1; mm < 64; mm <<= 1) {
      s0 += __shfl_xor(s0, mm);
      #pragma unroll
      for (int r = 0; r < 8; ++r) dd[r] += __shfl_xor(dd[r], mm);
    }
    float bv = -1.f; int bi = 0;
    #pragma unroll
    for (int r = 0; r < 8; ++r) {
      float d = sqr[r] + s0 - 2.f * dd[r];
      dloc[r] = d;
      if (d > bv) { bv = d; bi = rbase + r; }
    }
    if (lane == 0) { rv[wid] = bv; ri[wid] = bi; }
  }
  __syncthreads();
  if (t == 0) {
    float vv = rv[0]; int ii = ri[0];
    for (int w = 1; w < 8; ++w)
      if (rv[w] > vv || (rv[w] == vv && ri[w] < ii)) { vv = rv[w]; ii = ri[w]; }
    atomicExch(&bviA[b], __float_as_int(vv));
    atomicExch(&biA[b], ii);
    atomicAdd(&bar[0], 1);
  }
  // side partials during spin
  if (wid == 1) {
    #pragma unroll
    for (int c = 0; c < 3; ++c) {
      float m = fabsf(t2[c * NPTS + b * 64 + lane]);
      #pragma unroll
      for (int mm = 1; mm < 64; mm <<= 1) m = fmaxf(m, __shfl_xor(m, mm));
      if (lane == 0) tmpart[b * 3 + c] = m;
    }
  } else if (wid == 2) {
    int k = b * 64 + lane;
    float v = t2[k] + t2[NPTS + k] + t2[2 * NPTS + k];
    int ki = k;
    #pragma unroll
    for (int mm = 1; mm < 64; mm <<= 1) {
      float ov = __shfl_xor(v, mm); int oi = __shfl_xor(ki, mm);
      if (ov < v || (ov == v && oi < ki)) { v = ov; ki = oi; }
    }
    if (lane == 0) { kvp[b] = v; kip[b] = ki; }
  }
  if (t == 0) { while (aloadi(&bar[0]) < 64) __builtin_amdgcn_s_sleep(2); }
  __syncthreads();
  {
    float v = __int_as_float(aloadi(&bviA[lane]));
    int i = aloadi(&biA[lane]);
    #pragma unroll
    for (int mm = 1; mm < 64; mm <<= 1) {
      float ov = __shfl_xor(v, mm); int oi = __shfl_xor(i, mm);
      if (ov > v || (ov == v && oi < i)) { v = ov; i = oi; }
    }
    b1 = i;
  }

  // ===== fp1: c = h[b1] =====
  {
    float cr[8];
    const float4* cp = (const float4*)(h + (size_t)b1 * FIN);
    float4 u0 = cp[2 * lane], u1 = cp[2 * lane + 1];
    cr[0]=u0.x;cr[1]=u0.y;cr[2]=u0.z;cr[3]=u0.w;cr[4]=u1.x;cr[5]=u1.y;cr[6]=u1.z;cr[7]=u1.w;
    float s0 = 0.f;
    #pragma unroll
    for (int q = 0; q < 8; ++q) s0 = fmaf(cr[q], cr[q], s0);
    float dd[8];
    #pragma unroll
    for (int r = 0; r < 8; ++r) dd[r] = 0.f;
    #pragma unroll
    for (int r = 0; r < 8; ++r)
      #pragma unroll
      for (int q = 0; q < 8; ++q) dd[r] = fmaf(x[r][q], cr[q], dd[r]);
    #pragma unroll
    for (int mm = 1; mm < 64; mm <<= 1) {
      s0 += __shfl_xor(s0, mm);
      #pragma unroll
      for (int r = 0; r < 8; ++r) dd[r] += __shfl_xor(dd[r], mm);
    }
    float bv = -1.f; int bi = 0;
    #pragma unroll
    for (int r = 0; r < 8; ++r) {
      float d = fminf(sqr[r] + s0 - 2.f * dd[r], dloc[r]);
      dloc[r] = d;
      if (d > bv) { bv = d; bi = rbase + r; }
    }
    if (lane == 0) { rv[wid] = bv; ri[wid] = bi; }
  }
  __syncthreads();
  if (t == 0) {
    float vv = rv[0]; int ii = ri[0];
    for (int w = 1; w < 8; ++w)
      if (rv[w] > vv || (rv[w] == vv && ri[w] < ii)) { vv = rv[w]; ii = ri[w]; }
    atomicExch(&bviB[b], __float_as_int(vv));
    atomicExch(&biB[b], ii);
    atomicAdd(&bar[1], 1);
    while (aloadi(&bar[1]) < 64) __builtin_amdgcn_s_sleep(2);
  }
  __syncthreads();
  {
    float v = __int_as_float(aloadi(&bviB[lane]));
    int i = aloadi(&biB[lane]);
    #pragma unroll
    for (int mm = 1; mm < 64; mm <<= 1) {
      float ov = __shfl_xor(v, mm); int oi = __shfl_xor(i, mm);
      if (ov > v || (ov == v && oi < i)) { v = ov; i = oi; }
    }
    b2 = i;
  }

  // ===== Lloyd x10 =====
  for (int it = 0; it < 10; ++it) {
    float c0r[8], c1r[8], c2r[8];
    if (it == 0) {
      const float4* p0 = (const float4*)h;
      const float4* p1 = (const float4*)(h + (size_t)b1 * FIN);
      const float4* p2 = (const float4*)(h + (size_t)b2 * FIN);
      float4 u;
      u = p0[2*lane];   c0r[0]=u.x;c0r[1]=u.y;c0r[2]=u.z;c0r[3]=u.w;
      u = p0[2*lane+1]; c0r[4]=u.x;c0r[5]=u.y;c0r[6]=u.z;c0r[7]=u.w;
      u = p1[2*lane];   c1r[0]=u.x;c1r[1]=u.y;c1r[2]=u.z;c1r[3]=u.w;
      u = p1[2*lane+1]; c1r[4]=u.x;c1r[5]=u.y;c1r[6]=u.z;c1r[7]=u.w;
      u = p2[2*lane];   c2r[0]=u.x;c2r[1]=u.y;c2r[2]=u.z;c2r[3]=u.w;
      u = p2[2*lane+1]; c2r[4]=u.x;c2r[5]=u.y;c2r[6]=u.z;c2r[7]=u.w;
    } else {
      ull* acc = accum + (size_t)(it - 1) * 1536;
      float cn[3];
      #pragma unroll
      for (int c = 0; c < 3; ++c)
        cn[c] = fmaxf((float)aloadi(&cntAcc[(it - 1) * 4 + c]), 1.f);
      for (int idx = t; idx < 1536; idx += 512)
        cents[idx] = (float)(long long)aloadu(&acc[idx]) * INVSCALE / cn[idx >> 9];
      __syncthreads();
      float4 u;
      u = *(const float4*)&cents[8*lane];        c0r[0]=u.x;c0r[1]=u.y;c0r[2]=u.z;c0r[3]=u.w;
      u = *(const float4*)&cents[8*lane+4];      c0r[4]=u.x;c0r[5]=u.y;c0r[6]=u.z;c0r[7]=u.w;
      u = *(const float4*)&cents[512+8*lane];    c1r[0]=u.x;c1r[1]=u.y;c1r[2]=u.z;c1r[3]=u.w;
      u = *(const float4*)&cents[512+8*lane+4];  c1r[4]=u.x;c1r[5]=u.y;c1r[6]=u.z;c1r[7]=u.w;
      u = *(const float4*)&cents[1024+8*lane];   c2r[0]=u.x;c2r[1]=u.y;c2r[2]=u.z;c2r[3]=u.w;
      u = *(const float4*)&cents[1024+8*lane+4]; c2r[4]=u.x;c2r[5]=u.y;c2r[6]=u.z;c2r[7]=u.w;
    }
    float s0 = 0.f, s1 = 0.f, s2 = 0.f;
    #pragma unroll
    for (int q = 0; q < 8; ++q) {
      s0 = fmaf(c0r[q], c0r[q], s0); s1 = fmaf(c1r[q], c1r[q], s1); s2 = fmaf(c2r[q], c2r[q], s2);
    }
    #pragma unroll
    for (int mm = 1; mm < 64; mm <<= 1) {
      s0 += __shfl_xor(s0, mm); s1 += __shfl_xor(s1, mm); s2 += __shfl_xor(s2, mm);
    }
    float d[8][3];
    #pragma unroll
    for (int r = 0; r < 8; ++r) { d[r][0] = 0.f; d[r][1] = 0.f; d[r][2] = 0.f; }
    #pragma unroll
    for (int r = 0; r < 8; ++r)
      #pragma unroll
      for (int q = 0; q < 8; ++q) {
        d[r][0] = fmaf(x[r][q], c0r[q], d[r][0]);
        d[r][1] = fmaf(x[r][q], c1r[q], d[r][1]);
        d[r][2] = fmaf(x[r][q], c2r[q], d[r][2]);
      }
    #pragma unroll
    for (int mm = 1; mm < 64; mm <<= 1) {
      #pragma unroll
      for (int r = 0; r < 8; ++r) {
        d[r][0] += __shfl_xor(d[r][0], mm);
        d[r][1] += __shfl_xor(d[r][1], mm);
        d[r][2] += __shfl_xor(d[r][2], mm);
      }
    }
    float ps[3][8];
    #pragma unroll
    for (int c = 0; c < 3; ++c)
      #pragma unroll
      for (int q = 0; q < 8; ++q) ps[c][q] = 0.f;
    float cnt0 = 0.f, cnt1 = 0.f, cnt2 = 0.f;
    #pragma unroll
    for (int r = 0; r < 8; ++r) {
      float e0 = sqr[r] + s0 - 2.f * d[r][0];
      float e1 = sqr[r] + s1 - 2.f * d[r][1];
      float e2 = sqr[r] + s2 - 2.f * d[r][2];
      int bc = 0; float bd = e0;
      if (e1 < bd) { bd = e1; bc = 1; }
      if (e2 < bd) { bd = e2; bc = 2; }
      float f0 = bc == 0 ? 1.f : 0.f, f1 = bc == 1 ? 1.f : 0.f, f2 = bc == 2 ? 1.f : 0.f;
      #pragma unroll
      for (int q = 0; q < 8; ++q) {
        ps[0][q] = fmaf(f0, x[r][q], ps[0][q]);
        ps[1][q] = fmaf(f1, x[r][q], ps[1][q]);
        ps[2][q] = fmaf(f2, x[r][q], ps[2][q]);
      }
      cnt0 += f0; cnt1 += f1; cnt2 += f2;
    }
    #pragma unroll
    for (int c = 0; c < 3; ++c) {
      *(float4*)&wsum[wid * 1536 + c * 512 + 8 * lane]     = make_float4(ps[c][0], ps[c][1], ps[c][2], ps[c][3]);
      *(float4*)&wsum[wid * 1536 + c * 512 + 8 * lane + 4] = make_float4(ps[c][4], ps[c][5], ps[c][6], ps[c][7]);
    }
    if (lane == 0) { wcnt[wid * 3 + 0] = cnt0; wcnt[wid * 3 + 1] = cnt1; wcnt[wid * 3 + 2] = cnt2; }
    __syncthreads();
    ull* accO = accum + (size_t)it * 1536;
    for (int idx = t; idx < 1536; idx += 512) {
      float s = ((wsum[0*1536+idx] + wsum[1*1536+idx]) + (wsum[2*1536+idx] + wsum[3*1536+idx]))
              + ((wsum[4*1536+idx] + wsum[5*1536+idx]) + (wsum[6*1536+idx] + wsum[7*1536+idx]));
      long long q = llrintf(s * SCALE);
      atomicAdd(&accO[idx], (ull)q);           // non-returning
    }
    if (t < 3) {
      float s = 0.f;
      for (int w = 0; w < 8; ++w) s += wcnt[w * 3 + t];
      atomicAdd(&cntAcc[it * 4 + t], (int)(s + 0.5f));   // non-returning
    }
    if (it < 9) megabar(bar, 2 + it);
  }
}

// ---------------- mainC: centers/dc/tm + per-block d1v + softmax@Wh + out ----------------
__global__ __launch_bounds__(512) void k_mainC(
    const float* __restrict__ h, const float* __restrict__ sq,
    const float* __restrict__ t2, const __hip_bfloat16* __restrict__ WhbT,
    const float* __restrict__ Wh, const int* __restrict__ m1,
    const ull* __restrict__ accIn, const int* __restrict__ cntIn,
    const float* __restrict__ tmpart, const float* __restrict__ kvp,
    const int* __restrict__ kip, float* __restrict__ out) {
  __shared__ float t2s[3 * 4096];
  __shared__ float VcS[8][16][68];
  __shared__ float SpS[8][16];
  __shared__ float Mrow[16];
  __shared__ float a012[16][3];
  __shared__ float cents[1536];
  __shared__ float cntS[3];
  __shared__ float tmS[3];
  __shared__ float red[8];
  __shared__ int skstar;
  int t = threadIdx.x, lane = t & 63, wid = t >> 6;
  int R0 = blockIdx.x * 16;
  for (int idx = t; idx < 3072; idx += 512)
    ((f32x4*)t2s)[idx] = ((const f32x4*)t2)[idx];
  if (t < 3) {
    cntS[t] = fmaxf((float)cntIn[t], 1.f);
    float m = 0.f;
    for (int q = 0; q < 64; ++q) m = fmaxf(m, tmpart[q * 3 + t]);
    tmS[t] = m;
  }
  float sdc = 0.f;
  #pragma unroll
  for (int q = 0; q < 8; ++q)
    sdc += sqrtf(fmaxf(__int_as_float(m1[t + 512 * q]), 0.f));
  sdc = wsum64(sdc);
  if (lane == 0) red[wid] = sdc;
  __syncthreads();
  for (int idx = t; idx < 1536; idx += 512)
    cents[idx] = (float)(long long)accIn[idx] * INVSCALE / cntS[idx >> 9];
  __syncthreads();
  float dcv = (((red[0] + red[1]) + (red[2] + red[3])) + ((red[4] + red[5]) + (red[6] + red[7])))
            * (1.f / (float)NPTS);
  {
    float c0r[8], c1r[8], c2r[8];
    float4 u;
    u = *(const float4*)&cents[8 * lane];          c0r[0]=u.x;c0r[1]=u.y;c0r[2]=u.z;c0r[3]=u.w;
    u = *(const float4*)&cents[8 * lane + 4];      c0r[4]=u.x;c0r[5]=u.y;c0r[6]=u.z;c0r[7]=u.w;
    u = *(const float4*)&cents[512 + 8 * lane];    c1r[0]=u.x;c1r[1]=u.y;c1r[2]=u.z;c1r[3]=u.w;
    u = *(const float4*)&cents[512 + 8 * lane + 4];c1r[4]=u.x;c1r[5]=u.y;c1r[6]=u.z;c1r[7]=u.w;
    u = *(const float4*)&cents[1024 + 8 * lane];   c2r[0]=u.x;c2r[1]=u.y;c2r[2]=u.z;c2r[3]=u.w;
    u = *(const float4*)&cents[1024 + 8*lane + 4]; c2r[4]=u.x;c2r[5]=u.y;c2r[6]=u.z;c2r[7]=u.w;
    float s0 = 0.f, s1 = 0.f, s2 = 0.f;
    #pragma unroll
    for (int q = 0; q < 8; ++q) {
      s0 = fmaf(c0r[q], c0r[q], s0); s1 = fmaf(c1r[q], c1r[q], s1); s2 = fmaf(c2r[q], c2r[q], s2);
    }
    float xr2[2][8];
    #pragma unroll
    for (int rr = 0; rr < 2; ++rr) {
      int row = R0 + 2 * wid + rr;
      const float4* xr = (const float4*)(h + (size_t)row * FIN);
      float4 u0 = xr[2 * lane], u1 = xr[2 * lane + 1];
      xr2[rr][0]=u0.x; xr2[rr][1]=u0.y; xr2[rr][2]=u0.z; xr2[rr][3]=u0.w;
      xr2[rr][4]=u1.x; xr2[rr][5]=u1.y; xr2[rr][6]=u1.z; xr2[rr][7]=u1.w;
    }
    float dd[2][3];
    #pragma unroll
    for (int rr = 0; rr < 2; ++rr) { dd[rr][0]=0.f; dd[rr][1]=0.f; dd[rr][2]=0.f; }
    #pragma unroll
    for (int rr = 0; rr < 2; ++rr)
      #pragma unroll
      for (int q = 0; q < 8; ++q) {
        dd[rr][0] = fmaf(xr2[rr][q], c0r[q], dd[rr][0]);
        dd[rr][1] = fmaf(xr2[rr][q], c1r[q], dd[rr][1]);
        dd[rr][2] = fmaf(xr2[rr][q], c2r[q], dd[rr][2]);
      }
    #pragma unroll
    for (int mm = 1; mm < 64; mm <<= 1) {
      s0 += __shfl_xor(s0, mm); s1 += __shfl_xor(s1, mm); s2 += __shfl_xor(s2, mm);
      #pragma unroll
      for (int rr = 0; rr < 2; ++rr) {
        dd[rr][0] += __shfl_xor(dd[rr][0], mm);
        dd[rr][1] += __shfl_xor(dd[rr][1], mm);
        dd[rr][2] += __shfl_xor(dd[rr][2], mm);
      }
    }
    if (lane == 0) {
      #pragma unroll
      for (int rr = 0; rr < 2; ++rr) {
        int row = R0 + 2 * wid + rr;
        float sr = sq[row];
        float q0 = sqrtf(fmaxf(sr + s0 - 2.f * dd[rr][0], 0.f));
        float q1 = sqrtf(fmaxf(sr + s1 - 2.f * dd[rr][1], 0.f));
        float q2 = sqrtf(fmaxf(sr + s2 - 2.f * dd[rr][2], 0.f));
        float nr = q1;
        float a0 = (q0 != 0.f) ? (dcv * nr / (q0 * q0)) : 0.f;
        float a1 = (q1 != 0.f) ? (dcv * nr / (q1 * q1)) : 0.f;
        float a2 = (q2 != 0.f) ? (dcv * nr / (q2 * q2)) : 0.f;
        a012[2 * wid + rr][0] = a0; a012[2 * wid + rr][1] = a1; a012[2 * wid + rr][2] = a2;
        Mrow[2 * wid + rr] = fmaf(fabsf(a2), tmS[2], fmaf(fabsf(a1), tmS[1], fabsf(a0) * tmS[0]));
      }
    }
  }
  __syncthreads();
  int r16 = lane & 15, hi = lane >> 4;
  float a0 = a012[r16][0], a1 = a012[r16][1], a2 = a012[r16][2];
  float M = Mrow[r16];
  int K0 = wid * 512;
  f32x4 acc[4];
  #pragma unroll
  for (int fn = 0; fn < 4; ++fn) acc[fn] = (f32x4){0.f, 0.f, 0.f, 0.f};
  float Sp = 0.f;
  const __hip_bfloat16* bwB[4];
  #pragma unroll
  for (int fn = 0; fn < 4; ++fn)
    bwB[fn] = WhbT + (size_t)(fn * 16 + r16) * NPTS + K0 + hi * 8;

  for (int kst = 0; kst < 16; ++kst) {
    int kb = K0 + kst * 32 + hi * 8;
    f32x4 c0a = *(const f32x4*)&t2s[kb],        c0b = *(const f32x4*)&t2s[kb + 4];
    f32x4 c1a = *(const f32x4*)&t2s[4096 + kb], c1b = *(const f32x4*)&t2s[4096 + kb + 4];
    f32x4 c2a = *(const f32x4*)&t2s[8192 + kb], c2b = *(const f32x4*)&t2s[8192 + kb + 4];
    float pv[8];
    #pragma unroll
    for (int j = 0; j < 4; ++j) {
      float L  = fmaf(a0, c0a[j], fmaf(a1, c1a[j], fmaf(a2, c2a[j], -M)));
      pv[j] = __expf(L);
      float L2 = fmaf(a0, c0b[j], fmaf(a1, c1b[j], fmaf(a2, c2b[j], -M)));
      pv[4 + j] = __expf(L2);
    }
    Sp += ((pv[0] + pv[1]) + (pv[2] + pv[3])) + ((pv[4] + pv[5]) + (pv[6] + pv[7]));
    union { bf16x8 v; __hip_bfloat162 h2[4]; } pa;
    #pragma unroll
    for (int jj = 0; jj < 4; ++jj) {
      float2 f2; f2.x = pv[2 * jj]; f2.y = pv[2 * jj + 1];
      pa.h2[jj] = __float22bfloat162_rn(f2);
    }
    #pragma unroll
    for (int fn = 0; fn < 4; ++fn) {
      bf16x8 bw = *(const bf16x8*)(bwB[fn] + kst * 32);
      acc[fn] = __builtin_amdgcn_mfma_f32_16x16x32_bf16(pa.v, bw, acc[fn], 0, 0, 0);
    }
  }
  Sp += __shfl_xor(Sp, 16);
  Sp += __shfl_xor(Sp, 32);
  if (hi == 0) SpS[wid][r16] = Sp;
  #pragma unroll
  for (int fn = 0; fn < 4; ++fn)
    #pragma unroll
    for (int q = 0; q < 4; ++q)
      VcS[wid][hi * 4 + q][fn * 16 + r16] = acc[fn][q];
  __syncthreads();
  for (int e = t; e < 1024; e += 512) {
    int row = e >> 6, col = e & 63;
    float V = 0.f;
    #pragma unroll
    for (int w = 0; w < 8; ++w) V += VcS[w][row][col];
    float S = 3.f * __expf(-Mrow[row]);
    #pragma unroll
    for (int w = 0; w < 8; ++w) S += SpS[w][row];
    float o = V / S;
    out[(size_t)(R0 + row) * FOUT + col] = o > 0.f ? o : expm1f(o);
  }
  if (blockIdx.x == 0) {
    if (wid == 0) {
      float v = kvp[lane]; int i = kip[lane];
      #pragma unroll
      for (int mm = 1; mm < 64; mm <<= 1) {
        float ov = __shfl_xor(v, mm); int oi = __shfl_xor(i, mm);
        if (ov < v || (ov == v && oi < i)) { v = ov; i = oi; }
      }
      if (lane == 0) skstar = i;
    }
    __syncthreads();
    int kstar = skstar;
    if (t < 192) {
      int c = t >> 6, j = t & 63;
      float wv = Wh[(size_t)kstar * FOUT + j];
      out[(size_t)(NPTS + c) * FOUT + j] = wv > 0.f ? wv : expm1f(wv);
    }
  }
}

extern "C" void kernel_launch(void* const* d_in, const int* in_sizes, int n_in,
                              void* d_out, int out_size, void* d_ws, size_t ws_size,
                              hipStream_t stream) {
  const float* h  = (const float*)d_in[0];
  const float* W  = (const float*)d_in[2];
  const float* t2 = (const float*)d_in[5];
  float* out = (float*)d_out;

  char* ws = (char*)d_ws;
  __hip_bfloat16* xb = (__hip_bfloat16*)ws;
  float* F = (float*)(ws + (size_t)NPTS * FIN * 2);
  float* sq   = F + 0;
  int*   m1   = (int*)(F + 4096);
  float* Wh   = F + 32768;
  __hip_bfloat16* WhbT = (__hip_bfloat16*)(F + 1756672);
  __hip_bfloat16* WbT  = (__hip_bfloat16*)(F + 1887744);
  float* G = F + 1904128;
  int*   bviA   = (int*)(G + 0);
  int*   biA    = (int*)(G + 64);
  int*   bviB   = (int*)(G + 128);
  int*   biB    = (int*)(G + 192);
  float* tmpart = G + 384;
  float* kvp    = G + 576;
  int*   kip    = (int*)(G + 640);
  int*   bar    = (int*)(G + 704);          // 32 ints
  ull*   accum  = (ull*)(G + 768);          // 10 * 1536 ull
  int*   cntAcc = (int*)(G + 768 + 30720);  // 10 * 4 int

  k_prep<<<1032, 256, 0, stream>>>(h, W, xb, sq, m1, WbT, accum, cntAcc, bar);
  k_mega<<<624, 512, 0, stream>>>(h, sq, xb, m1, t2, bviA, biA, bviB, biB,
                                  tmpart, kvp, kip, accum, cntAcc, bar, WbT, Wh, WhbT);
  k_mainC<<<256, 512, 0, stream>>>(h, sq, t2, WhbT, Wh, m1,
                                   (const ull*)(accum + 9 * 1536), (const int*)(cntAcc + 9 * 4),
                                   tmpart, kvp, kip, out);
}